// Round 11
// baseline (1103.712 us; speedup 1.0000x reference)
//
#include <hip/hip_runtime.h>
#include <math.h>

#define N_NODES 50000
#define N_EDGES 1000000
#define HID 64
#define SCAN_NB ((N_NODES + 1 + 255) / 256)
#define N_TILES (N_NODES / 16)          // 3125 (exact)
#define NB_F ((N_TILES + 3) / 4)        // 782 fused blocks (4 waves each)
static_assert(N_NODES % 16 == 0, "tile math");
static_assert(N_NODES <= 65536, "src must fit in 16 bits");

typedef __attribute__((ext_vector_type(8))) short short8;   // 8 bf16 = 4 VGPRs
typedef __attribute__((ext_vector_type(4))) float f32x4;

__device__ __forceinline__ unsigned short f2bf(float x) {   // RNE float->bf16
    unsigned u = __float_as_uint(x);
    u += 0x7FFFu + ((u >> 16) & 1u);
    return (unsigned short)(u >> 16);
}
__device__ __forceinline__ float bfbits_hi(unsigned pk) {   // high-16 bf16 -> f32
    return __uint_as_float(pk & 0xFFFF0000u);
}
__device__ __forceinline__ float bf2f(unsigned short v) {
    return __uint_as_float(((unsigned)v) << 16);
}

// ---------------- node encoder: h = x @ W_node + b_node (f32 + bf16 copies) ----------------
__global__ __launch_bounds__(256) void k_node_encode(
    const float* __restrict__ x, const float* __restrict__ Wn,
    const float* __restrict__ bn, float* __restrict__ h, unsigned short* __restrict__ hb) {
    int n = blockIdx.x * 4 + (threadIdx.x >> 6);
    int c = threadIdx.x & 63;
    if (n >= N_NODES) return;
    float acc = bn[c];
    const float* xr = x + n * 16;
    #pragma unroll
    for (int k = 0; k < 16; ++k) acc = fmaf(xr[k], Wn[k * 64 + c], acc);
    h[n * 64 + c] = acc;
    hb[n * 64 + c] = f2bf(acc);
}

// ---------------- edge CSR build: histogram + per-edge rank ----------------
__global__ __launch_bounds__(256) void k_hist_rank(const int* __restrict__ ei,
                                                   int* __restrict__ cnt, int* __restrict__ rank) {
    int i = blockIdx.x * blockDim.x + threadIdx.x;
    if (i >= N_EDGES) return;
    rank[i] = atomicAdd(&cnt[ei[N_EDGES + i]], 1);
}

__global__ __launch_bounds__(256) void k_scan1(const int* __restrict__ cnt,
                                               int* __restrict__ inc, int* __restrict__ bsum) {
    __shared__ int sh[256];
    int gi = blockIdx.x * 256 + threadIdx.x;
    int v = (gi < N_NODES + 1) ? cnt[gi] : 0;
    sh[threadIdx.x] = v;
    __syncthreads();
    #pragma unroll
    for (int d = 1; d < 256; d <<= 1) {
        int t = (threadIdx.x >= d) ? sh[threadIdx.x - d] : 0;
        __syncthreads();
        sh[threadIdx.x] += t;
        __syncthreads();
    }
    if (gi < N_NODES + 1) inc[gi] = sh[threadIdx.x];
    if (threadIdx.x == 255) bsum[blockIdx.x] = sh[255];
}

__global__ __launch_bounds__(256) void k_scan2(int* __restrict__ bsum) {
    __shared__ int sh[256];
    int t = threadIdx.x;
    sh[t] = (t < SCAN_NB) ? bsum[t] : 0;
    __syncthreads();
    #pragma unroll
    for (int d = 1; d < 256; d <<= 1) {
        int v = (t >= d) ? sh[t - d] : 0;
        __syncthreads();
        sh[t] += v;
        __syncthreads();
    }
    if (t < SCAN_NB) bsum[t] = (t == 0) ? 0 : sh[t - 1];
}

__global__ __launch_bounds__(256) void k_scan3(const int* __restrict__ inc,
                                               const int* __restrict__ cnt,
                                               const int* __restrict__ bsum,
                                               int* __restrict__ offs) {
    int gi = blockIdx.x * 256 + threadIdx.x;
    if (gi < N_NODES + 1) offs[gi] = bsum[blockIdx.x] + inc[gi] - cnt[gi];
}

// pure random 4B store, no atomics: p = offs[d] + rank[i]
__global__ __launch_bounds__(256) void k_scatter(
    const int* __restrict__ ei, const float* __restrict__ eattr,
    const int* __restrict__ offs, const int* __restrict__ rank,
    unsigned int* __restrict__ s_pack) {
    int i = blockIdx.x * blockDim.x + threadIdx.x;
    if (i >= N_EDGES) return;
    int d = ei[N_EDGES + i];
    int p = offs[d] + rank[i];
    unsigned pk = ((unsigned)f2bf(eattr[i]) << 16) | (unsigned)(ei[i] & 0xFFFF);
    s_pack[p] = pk;
}

// ---------------- fused layer: agg (16 nodes/wave) + MFMA MLP + epilogue ----------------
// mode 0: layer0  — no residual, write h, write zbout (next norm)
// mode 1: layer1  — residual,   write h, write zbout (next norm)
// mode 2: layer2  — residual,   no h write, pool partials (norm_g[0])
__global__ __launch_bounds__(256) void k_fused(
    const unsigned short* __restrict__ zbin, unsigned short* __restrict__ zbout,
    float* __restrict__ h,
    const int* __restrict__ offs, const unsigned int* __restrict__ s_pack,
    const float* __restrict__ We, const float* __restrict__ be,
    const float* __restrict__ temp, int layer,
    const float* __restrict__ W1, const float* __restrict__ b1,
    const float* __restrict__ g1, const float* __restrict__ be1,
    const float* __restrict__ W2, const float* __restrict__ b2,
    const float* __restrict__ ng, const float* __restrict__ nb,
    int mode, float* __restrict__ pb_sum, float* __restrict__ pb_max) {
    __shared__ unsigned short vbuf[4][16 * 64];
    __shared__ unsigned short ubuf[4][16 * 128];
    __shared__ float lssum[4][4][16], lsmax[4][4][16];
    int lane = threadIdx.x & 63;
    int wave = threadIdx.x >> 6;
    int col = lane & 15, quad = lane >> 4;
    unsigned short* vb = vbuf[wave];
    unsigned short* ub = ubuf[wave];

    // weight B-fragments in VGPRs (bf16)
    short8 w1f[2][8];
    #pragma unroll
    for (int s = 0; s < 2; ++s)
        #pragma unroll
        for (int t = 0; t < 8; ++t)
            #pragma unroll
            for (int j = 0; j < 8; ++j)
                w1f[s][t][j] = (short)f2bf(W1[(s * 32 + quad * 8 + j) * 128 + t * 16 + col]);
    short8 w2f[4][4];
    #pragma unroll
    for (int s = 0; s < 4; ++s)
        #pragma unroll
        for (int t = 0; t < 4; ++t)
            #pragma unroll
            for (int j = 0; j < 8; ++j)
                w2f[s][t][j] = (short)f2bf(W2[(s * 32 + quad * 8 + j) * 64 + t * 16 + col]);

    float b1f[8], g1f[8], e1f[8];
    #pragma unroll
    for (int t = 0; t < 8; ++t) {
        int ch = t * 16 + col;
        b1f[t] = b1[ch]; g1f[t] = g1[ch]; e1f[t] = be1[ch];
    }
    float b2f_[4], ngf[4], nbf[4];
    #pragma unroll
    for (int t = 0; t < 4; ++t) {
        b2f_[t] = b2[t * 16 + col];
        ngf[t] = ng[t * 16 + col];
        nbf[t] = nb[t * 16 + col];
    }

    float psum[4] = {0.f, 0.f, 0.f, 0.f};
    float pmax[4] = {0.f, 0.f, 0.f, 0.f};

    int tile = blockIdx.x * 4 + wave;
    bool active = tile < N_TILES;
    if (active) {
        int n0 = tile * 16;
        float we = We[lane], bev = be[lane];
        float tl = temp[layer];
        // ---- aggregation: 16 nodes sequentially, shift-free online softmax ----
        for (int k = 0; k < 16; ++k) {
            int n = n0 + k;
            int beg = offs[n], end = offs[n + 1];
            float s = 0.f, num = 0.f;
            int i = beg;
            for (; i + 3 < end; i += 4) {
                unsigned pk0 = s_pack[i], pk1 = s_pack[i + 1];
                unsigned pk2 = s_pack[i + 2], pk3 = s_pack[i + 3];
                float z0 = bf2f(zbin[(pk0 & 0xFFFFu) * 64 + lane]);
                float z1 = bf2f(zbin[(pk1 & 0xFFFFu) * 64 + lane]);
                float z2 = bf2f(zbin[(pk2 & 0xFFFFu) * 64 + lane]);
                float z3 = bf2f(zbin[(pk3 & 0xFFFFu) * 64 + lane]);
                float msg0 = fmaxf(z0 + fmaf(bfbits_hi(pk0), we, bev), 0.f) + 1e-7f;
                float msg1 = fmaxf(z1 + fmaf(bfbits_hi(pk1), we, bev), 0.f) + 1e-7f;
                float msg2 = fmaxf(z2 + fmaf(bfbits_hi(pk2), we, bev), 0.f) + 1e-7f;
                float msg3 = fmaxf(z3 + fmaf(bfbits_hi(pk3), we, bev), 0.f) + 1e-7f;
                float p0 = __expf(msg0 * tl), p1 = __expf(msg1 * tl);
                float p2 = __expf(msg2 * tl), p3 = __expf(msg3 * tl);
                s += (p0 + p1) + (p2 + p3);
                num += fmaf(p0, msg0, p1 * msg1) + fmaf(p2, msg2, p3 * msg3);
            }
            for (; i < end; ++i) {
                unsigned pk = s_pack[i];
                float zz = bf2f(zbin[(pk & 0xFFFFu) * 64 + lane]);
                float msg = fmaxf(zz + fmaf(bfbits_hi(pk), we, bev), 0.f) + 1e-7f;
                float p = __expf(msg * tl);
                s += p;
                num = fmaf(p, msg, num);
            }
            float v = num / (s + 1e-16f) + bf2f(zbin[(size_t)n * 64 + lane]);
            vb[k * 64 + lane] = f2bf(v);
        }
        // ---- GEMM1: u = v @ W1 ----
        short8 af0 = *(const short8*)&vb[col * 64 + quad * 8];
        short8 af1 = *(const short8*)&vb[col * 64 + 32 + quad * 8];
        f32x4 au[8];
        #pragma unroll
        for (int t = 0; t < 8; ++t) {
            f32x4 c = {0.f, 0.f, 0.f, 0.f};
            c = __builtin_amdgcn_mfma_f32_16x16x32_bf16(af0, w1f[0][t], c, 0, 0, 0);
            c = __builtin_amdgcn_mfma_f32_16x16x32_bf16(af1, w1f[1][t], c, 0, 0, 0);
            au[t] = c;
        }
        // ---- LN(128)+relu in C-layout; u bf16 -> LDS ----
        #pragma unroll
        for (int r = 0; r < 4; ++r) {
            float sx = 0.f, sq = 0.f;
            #pragma unroll
            for (int t = 0; t < 8; ++t) {
                float v = au[t][r] + b1f[t];
                sx += v; sq += v * v;
            }
            #pragma unroll
            for (int mask = 1; mask < 16; mask <<= 1) {
                sx += __shfl_xor(sx, mask, 64);
                sq += __shfl_xor(sq, mask, 64);
            }
            float mu = sx * (1.f / 128.f);
            float var = sq * (1.f / 128.f) - mu * mu;
            float rs = rsqrtf(var + 1e-5f);
            int row = quad * 4 + r;
            #pragma unroll
            for (int t = 0; t < 8; ++t) {
                float v = au[t][r] + b1f[t];
                float y = fmaxf(fmaf((v - mu) * rs, g1f[t], e1f[t]), 0.f);
                ub[row * 128 + t * 16 + col] = f2bf(y);
            }
        }
        // ---- GEMM2: o = u @ W2 ----
        f32x4 oc[4];
        #pragma unroll
        for (int t = 0; t < 4; ++t) oc[t] = (f32x4){0.f, 0.f, 0.f, 0.f};
        #pragma unroll
        for (int s = 0; s < 4; ++s) {
            short8 a = *(const short8*)&ub[col * 128 + s * 32 + quad * 8];
            #pragma unroll
            for (int t = 0; t < 4; ++t)
                oc[t] = __builtin_amdgcn_mfma_f32_16x16x32_bf16(a, w2f[s][t], oc[t], 0, 0, 0);
        }
        // ---- epilogue: bias (+res) -> h/zbout or pool partials ----
        #pragma unroll
        for (int r = 0; r < 4; ++r) {
            int n = n0 + quad * 4 + r;
            float val[4];
            #pragma unroll
            for (int t = 0; t < 4; ++t) {
                val[t] = oc[t][r] + b2f_[t];
                if (mode >= 1) val[t] += h[(size_t)n * 64 + t * 16 + col];
            }
            if (mode <= 1) {
                #pragma unroll
                for (int t = 0; t < 4; ++t) h[(size_t)n * 64 + t * 16 + col] = val[t];
            }
            // LN(64) across quad lanes (in-lane 4 ch + 4-step intra-quad shuffle)
            float sx = 0.f, sq = 0.f;
            #pragma unroll
            for (int t = 0; t < 4; ++t) { sx += val[t]; sq += val[t] * val[t]; }
            #pragma unroll
            for (int mask = 1; mask < 16; mask <<= 1) {
                sx += __shfl_xor(sx, mask, 64);
                sq += __shfl_xor(sq, mask, 64);
            }
            float mu = sx * (1.f / 64.f);
            float var = sq * (1.f / 64.f) - mu * mu;
            float rs = rsqrtf(var + 1e-5f);
            #pragma unroll
            for (int t = 0; t < 4; ++t) {
                float y = fmaxf(fmaf((val[t] - mu) * rs, ngf[t], nbf[t]), 0.f);
                if (mode <= 1) {
                    zbout[(size_t)n * 64 + t * 16 + col] = f2bf(y);
                } else {
                    psum[t] += y;
                    pmax[t] = fmaxf(pmax[t], y);
                }
            }
        }
    }
    if (mode == 2) {
        // cross-quad combine (channels replicate across quads)
        #pragma unroll
        for (int t = 0; t < 4; ++t) {
            psum[t] += __shfl_xor(psum[t], 16, 64);
            psum[t] += __shfl_xor(psum[t], 32, 64);
            pmax[t] = fmaxf(pmax[t], __shfl_xor(pmax[t], 16, 64));
            pmax[t] = fmaxf(pmax[t], __shfl_xor(pmax[t], 32, 64));
        }
        if (quad == 0) {
            #pragma unroll
            for (int t = 0; t < 4; ++t) {
                lssum[wave][t][col] = psum[t];
                lsmax[wave][t][col] = pmax[t];
            }
        }
        __syncthreads();
        if (wave == 0) {
            int t = lane >> 4, c = lane & 15;   // ch = lane
            float s = lssum[0][t][c] + lssum[1][t][c] + lssum[2][t][c] + lssum[3][t][c];
            float mx = fmaxf(fmaxf(lsmax[0][t][c], lsmax[1][t][c]),
                             fmaxf(lsmax[2][t][c], lsmax[3][t][c]));
            pb_sum[blockIdx.x * 64 + lane] = s;
            pb_max[blockIdx.x * 64 + lane] = mx;
        }
    }
}

// ---------------- head: reduce block partials -> bins -> emb @ W_lin + b_lin ----------------
__global__ __launch_bounds__(256) void k_head(
    const float* __restrict__ pb_sum, const float* __restrict__ pb_max,
    const float* __restrict__ Wl, const float* __restrict__ bl, float* __restrict__ out) {
    __shared__ float sa4[4][64], sm4[4][64];
    __shared__ float sa[64], sm[64], emb[64];
    int t = threadIdx.x;
    int ch = t & 63, part = t >> 6;
    float s = 0.f, mx = 0.f;
    for (int b = part; b < NB_F; b += 4) {
        s += pb_sum[b * 64 + ch];
        mx = fmaxf(mx, pb_max[b * 64 + ch]);
    }
    sa4[part][ch] = s; sm4[part][ch] = mx;
    __syncthreads();
    if (t < 64) {
        sa[t] = sa4[0][t] + sa4[1][t] + sa4[2][t] + sa4[3][t];
        sm[t] = fmaxf(fmaxf(sm4[0][t], sm4[1][t]), fmaxf(sm4[2][t], sm4[3][t]));
    }
    __syncthreads();
    if (t < 64) {
        if (t < 32) {
            emb[t] = (sa[2 * t] + sa[2 * t + 1]) * (0.5f / (float)N_NODES);
        } else {
            int i = t - 32;
            emb[t] = fmaxf(sm[2 * i], sm[2 * i + 1]);
        }
    }
    __syncthreads();
    if (t < 64) {
        float acc = bl[t];
        for (int k = 0; k < 64; ++k) acc = fmaf(emb[k], Wl[k * 64 + t], acc);
        out[t] = acc;
    }
}

extern "C" void kernel_launch(void* const* d_in, const int* in_sizes, int n_in,
                              void* d_out, int out_size, void* d_ws, size_t ws_size,
                              hipStream_t stream) {
    const float* x     = (const float*)d_in[0];
    const float* eattr = (const float*)d_in[1];
    const int*   ei    = (const int*)d_in[2];
    const float* Wn    = (const float*)d_in[3];
    const float* bn    = (const float*)d_in[4];
    const float* We    = (const float*)d_in[5];
    const float* be    = (const float*)d_in[6];
    const float* t     = (const float*)d_in[7];
    const float* W1    = (const float*)d_in[8];
    const float* b1    = (const float*)d_in[9];
    const float* lg    = (const float*)d_in[10];
    const float* lb    = (const float*)d_in[11];
    const float* W2    = (const float*)d_in[12];
    const float* b2    = (const float*)d_in[13];
    const float* ng    = (const float*)d_in[14];
    const float* nb    = (const float*)d_in[15];
    const float* Wl    = (const float*)d_in[16];
    const float* bl    = (const float*)d_in[17];
    float* out = (float*)d_out;

    char* p = (char*)d_ws;
    float* h   = (float*)p; p += (size_t)N_NODES * 64 * 4;
    unsigned short* zb0 = (unsigned short*)p; p += (size_t)N_NODES * 64 * 2;
    unsigned short* zb1 = (unsigned short*)p; p += (size_t)N_NODES * 64 * 2;
    unsigned int* s_pack = (unsigned int*)p; p += (size_t)N_EDGES * 4;
    int* cnt    = (int*)p;  p += (size_t)(N_NODES + 4) * 4;
    int* offs   = (int*)p;  p += (size_t)(N_NODES + 4) * 4;
    int* inc    = (int*)p;  p += (size_t)(N_NODES + 4) * 4;
    int* bsum   = (int*)p;  p += (size_t)256 * 4;
    float* pb_sum = (float*)p; p += (size_t)NB_F * 64 * 4;
    float* pb_max = (float*)p; p += (size_t)NB_F * 64 * 4;
    int* rank = (int*)p;    p += (size_t)N_EDGES * 4;

    hipMemsetAsync(cnt, 0, (N_NODES + 1) * sizeof(int), stream);

    k_node_encode<<<(N_NODES + 3) / 4, 256, 0, stream>>>(x, Wn, bn, h, zb0);
    k_hist_rank<<<(N_EDGES + 255) / 256, 256, 0, stream>>>(ei, cnt, rank);
    k_scan1<<<SCAN_NB, 256, 0, stream>>>(cnt, inc, bsum);
    k_scan2<<<1, 256, 0, stream>>>(bsum);
    k_scan3<<<SCAN_NB, 256, 0, stream>>>(inc, cnt, bsum, offs);
    k_scatter<<<(N_EDGES + 255) / 256, 256, 0, stream>>>(ei, eattr, offs, rank, s_pack);

    // layer 0: in zb0, out zb1 (norm for layer 1)
    k_fused<<<NB_F, 256, 0, stream>>>(zb0, zb1, h, offs, s_pack, We, be, t, 0,
                                      W1, b1, lg, lb, W2, b2,
                                      ng + 64, nb + 64, 0, pb_sum, pb_max);
    // layer 1: in zb1, out zb0 (norm for layer 2)
    k_fused<<<NB_F, 256, 0, stream>>>(zb1, zb0, h, offs, s_pack, We, be, t, 1,
                                      W1 + 64 * 128, b1 + 128, lg + 128, lb + 128,
                                      W2 + 128 * 64, b2 + 64,
                                      ng + 128, nb + 128, 1, pb_sum, pb_max);
    // layer 2: in zb0, pool with norm_g[0]
    k_fused<<<NB_F, 256, 0, stream>>>(zb0, zb1, h, offs, s_pack, We, be, t, 2,
                                      W1 + 2 * 64 * 128, b1 + 2 * 128, lg + 2 * 128, lb + 2 * 128,
                                      W2 + 2 * 128 * 64, b2 + 2 * 64,
                                      ng, nb, 2, pb_sum, pb_max);

    k_head<<<1, 256, 0, stream>>>(pb_sum, pb_max, Wl, bl, out);
}

// Round 12
// 428.623 us; speedup vs baseline: 2.5750x; 2.5750x over previous
//
#include <hip/hip_runtime.h>
#include <math.h>

#define N_NODES 50000
#define N_EDGES 1000000
#define HID 64
#define SCAN_NB ((N_NODES + 1 + 255) / 256)
#define N_TILES (N_NODES / 16)          // 3125
#define NB_F ((N_TILES + 3) / 4)        // 782 mlp blocks (4 waves each)
static_assert(N_NODES % 16 == 0, "tile math");
static_assert(N_NODES <= 65536, "src must fit in 16 bits");

typedef __attribute__((ext_vector_type(8))) short short8;   // 8 bf16 = 4 VGPRs
typedef __attribute__((ext_vector_type(4))) float f32x4;

__device__ __forceinline__ unsigned short f2bf(float x) {   // RNE float->bf16
    unsigned u = __float_as_uint(x);
    u += 0x7FFFu + ((u >> 16) & 1u);
    return (unsigned short)(u >> 16);
}
__device__ __forceinline__ float bfbits_hi(unsigned pk) {   // high-16 bf16 -> f32
    return __uint_as_float(pk & 0xFFFF0000u);
}
__device__ __forceinline__ float bf2f(unsigned short v) {
    return __uint_as_float(((unsigned)v) << 16);
}
// packed bf16 pair add with RNE re-round
__device__ __forceinline__ unsigned addpk(unsigned a, unsigned b) {
    float lo = __uint_as_float(a << 16) + __uint_as_float(b << 16);
    float hi = __uint_as_float(a & 0xFFFF0000u) + __uint_as_float(b & 0xFFFF0000u);
    return (unsigned)f2bf(lo) | ((unsigned)f2bf(hi) << 16);
}

// ---------------- node encoder: h = x @ W_node + b_node (f32 + bf16 copies) ----------------
__global__ __launch_bounds__(256) void k_node_encode(
    const float* __restrict__ x, const float* __restrict__ Wn,
    const float* __restrict__ bn, float* __restrict__ h, unsigned short* __restrict__ hb) {
    int n = blockIdx.x * 4 + (threadIdx.x >> 6);
    int c = threadIdx.x & 63;
    if (n >= N_NODES) return;
    float acc = bn[c];
    const float* xr = x + n * 16;
    #pragma unroll
    for (int k = 0; k < 16; ++k) acc = fmaf(xr[k], Wn[k * 64 + c], acc);
    h[n * 64 + c] = acc;
    hb[n * 64 + c] = f2bf(acc);
}

// ---------------- edge CSR build ----------------
__global__ __launch_bounds__(256) void k_hist_rank(const int* __restrict__ ei,
                                                   int* __restrict__ cnt, int* __restrict__ rank) {
    int i = blockIdx.x * blockDim.x + threadIdx.x;
    if (i >= N_EDGES) return;
    rank[i] = atomicAdd(&cnt[ei[N_EDGES + i]], 1);
}

__global__ __launch_bounds__(256) void k_scan1(const int* __restrict__ cnt,
                                               int* __restrict__ inc, int* __restrict__ bsum) {
    __shared__ int sh[256];
    int gi = blockIdx.x * 256 + threadIdx.x;
    int v = (gi < N_NODES + 1) ? cnt[gi] : 0;
    sh[threadIdx.x] = v;
    __syncthreads();
    #pragma unroll
    for (int d = 1; d < 256; d <<= 1) {
        int t = (threadIdx.x >= d) ? sh[threadIdx.x - d] : 0;
        __syncthreads();
        sh[threadIdx.x] += t;
        __syncthreads();
    }
    if (gi < N_NODES + 1) inc[gi] = sh[threadIdx.x];
    if (threadIdx.x == 255) bsum[blockIdx.x] = sh[255];
}

__global__ __launch_bounds__(256) void k_scan2(int* __restrict__ bsum) {
    __shared__ int sh[256];
    int t = threadIdx.x;
    sh[t] = (t < SCAN_NB) ? bsum[t] : 0;
    __syncthreads();
    #pragma unroll
    for (int d = 1; d < 256; d <<= 1) {
        int v = (t >= d) ? sh[t - d] : 0;
        __syncthreads();
        sh[t] += v;
        __syncthreads();
    }
    if (t < SCAN_NB) bsum[t] = (t == 0) ? 0 : sh[t - 1];
}

__global__ __launch_bounds__(256) void k_scan3(const int* __restrict__ inc,
                                               const int* __restrict__ cnt,
                                               const int* __restrict__ bsum,
                                               int* __restrict__ offs) {
    int gi = blockIdx.x * 256 + threadIdx.x;
    if (gi < N_NODES + 1) offs[gi] = bsum[blockIdx.x] + inc[gi] - cnt[gi];
}

__global__ __launch_bounds__(256) void k_scatter(
    const int* __restrict__ ei, const float* __restrict__ eattr,
    const int* __restrict__ offs, const int* __restrict__ rank,
    unsigned int* __restrict__ s_pack) {
    int i = blockIdx.x * blockDim.x + threadIdx.x;
    if (i >= N_EDGES) return;
    int d = ei[N_EDGES + i];
    int p = offs[d] + rank[i];
    unsigned pk = ((unsigned)f2bf(eattr[i]) << 16) | (unsigned)(ei[i] & 0xFFFF);
    s_pack[p] = pk;
}

// ---------------- softmax aggregation (shift-free), one wave/node, low-VGPR high-TLP ----------------
__global__ __launch_bounds__(256) void k_agg(
    const unsigned short* __restrict__ zb, const int* __restrict__ offs,
    const unsigned int* __restrict__ s_pack,
    const float* __restrict__ We, const float* __restrict__ be,
    const float* __restrict__ t, int layer, unsigned short* __restrict__ aggb) {
    int wid = (blockIdx.x * blockDim.x + threadIdx.x) >> 6;
    int lane = threadIdx.x & 63;
    if (wid >= N_NODES) return;
    int beg = offs[wid], end = offs[wid + 1];
    float we = We[lane], bev = be[lane];
    float tl = t[layer];
    float s = 0.f, num = 0.f;
    int i = beg;
    for (; i + 3 < end; i += 4) {
        unsigned pk0 = s_pack[i], pk1 = s_pack[i + 1], pk2 = s_pack[i + 2], pk3 = s_pack[i + 3];
        float z0 = bf2f(zb[(pk0 & 0xFFFFu) * 64 + lane]);
        float z1 = bf2f(zb[(pk1 & 0xFFFFu) * 64 + lane]);
        float z2 = bf2f(zb[(pk2 & 0xFFFFu) * 64 + lane]);
        float z3 = bf2f(zb[(pk3 & 0xFFFFu) * 64 + lane]);
        float msg0 = fmaxf(z0 + fmaf(bfbits_hi(pk0), we, bev), 0.f) + 1e-7f;
        float msg1 = fmaxf(z1 + fmaf(bfbits_hi(pk1), we, bev), 0.f) + 1e-7f;
        float msg2 = fmaxf(z2 + fmaf(bfbits_hi(pk2), we, bev), 0.f) + 1e-7f;
        float msg3 = fmaxf(z3 + fmaf(bfbits_hi(pk3), we, bev), 0.f) + 1e-7f;
        float p0 = __expf(msg0 * tl), p1 = __expf(msg1 * tl);
        float p2 = __expf(msg2 * tl), p3 = __expf(msg3 * tl);
        s += (p0 + p1) + (p2 + p3);
        num += fmaf(p0, msg0, p1 * msg1) + fmaf(p2, msg2, p3 * msg3);
    }
    for (; i < end; ++i) {
        unsigned pk = s_pack[i];
        float zz = bf2f(zb[(pk & 0xFFFFu) * 64 + lane]);
        float msg = fmaxf(zz + fmaf(bfbits_hi(pk), we, bev), 0.f) + 1e-7f;
        float p = __expf(msg * tl);
        s += p;
        num = fmaf(p, msg, num);
    }
    aggb[wid * 64 + lane] = f2bf(num / (s + 1e-16f));
}

// ---------------- MFMA MLP + fused epilogue ----------------
// mode 0: layer0 — no residual, write h, zb <- relu(LN(h, ng, nb)) in place
// mode 1: layer1 — residual,    write h, zb <- relu(LN(h, ng, nb)) in place
// mode 2: layer2 — residual, no h write, pool partials with ng/nb
__global__ __launch_bounds__(256) void k_mlp(
    const unsigned short* __restrict__ aggb, unsigned short* __restrict__ zb,
    float* __restrict__ h, const float* __restrict__ W1, const float* __restrict__ b1,
    const float* __restrict__ g1, const float* __restrict__ be1,
    const float* __restrict__ W2, const float* __restrict__ b2,
    const float* __restrict__ ng, const float* __restrict__ nb, int mode,
    float* __restrict__ pb_sum, float* __restrict__ pb_max) {
    __shared__ unsigned short vbuf[4][16 * 64];
    __shared__ unsigned short ubuf[4][16 * 128];
    __shared__ float lssum[4][4][16], lsmax[4][4][16];
    int lane = threadIdx.x & 63;
    int wave = threadIdx.x >> 6;
    int col = lane & 15, quad = lane >> 4;
    unsigned short* vb = vbuf[wave];
    unsigned short* ub = ubuf[wave];

    short8 w1f[2][8];
    #pragma unroll
    for (int s = 0; s < 2; ++s)
        #pragma unroll
        for (int t = 0; t < 8; ++t)
            #pragma unroll
            for (int j = 0; j < 8; ++j)
                w1f[s][t][j] = (short)f2bf(W1[(s * 32 + quad * 8 + j) * 128 + t * 16 + col]);
    short8 w2f[4][4];
    #pragma unroll
    for (int s = 0; s < 4; ++s)
        #pragma unroll
        for (int t = 0; t < 4; ++t)
            #pragma unroll
            for (int j = 0; j < 8; ++j)
                w2f[s][t][j] = (short)f2bf(W2[(s * 32 + quad * 8 + j) * 64 + t * 16 + col]);

    float b1f[8], g1f[8], e1f[8];
    #pragma unroll
    for (int t = 0; t < 8; ++t) {
        int ch = t * 16 + col;
        b1f[t] = b1[ch]; g1f[t] = g1[ch]; e1f[t] = be1[ch];
    }
    float b2f_[4], ngf[4], nbf[4];
    #pragma unroll
    for (int t = 0; t < 4; ++t) {
        b2f_[t] = b2[t * 16 + col];
        ngf[t] = ng[t * 16 + col];
        nbf[t] = nb[t * 16 + col];
    }

    float psum[4] = {0.f, 0.f, 0.f, 0.f};
    float pmax[4] = {0.f, 0.f, 0.f, 0.f};
    int nd = lane >> 2;
    int cg = (lane & 3) * 16;
    int tile = blockIdx.x * 4 + wave;

    if (tile < N_TILES) {
        int n0 = tile * 16;
        // stage v = bf16(aggb + zb) into LDS [16][64]
        const uint4* ap = (const uint4*)(aggb + (size_t)(n0 + nd) * 64 + cg);
        const uint4* zp = (const uint4*)(zb + (size_t)(n0 + nd) * 64 + cg);
        uint4 a0 = ap[0], a1 = ap[1], z0 = zp[0], z1 = zp[1];
        uint4 r0, r1;
        r0.x = addpk(a0.x, z0.x); r0.y = addpk(a0.y, z0.y);
        r0.z = addpk(a0.z, z0.z); r0.w = addpk(a0.w, z0.w);
        r1.x = addpk(a1.x, z1.x); r1.y = addpk(a1.y, z1.y);
        r1.z = addpk(a1.z, z1.z); r1.w = addpk(a1.w, z1.w);
        uint4* vdst = (uint4*)&vb[nd * 64 + cg];
        vdst[0] = r0;
        vdst[1] = r1;

        // GEMM1
        short8 af0 = *(const short8*)&vb[col * 64 + quad * 8];
        short8 af1 = *(const short8*)&vb[col * 64 + 32 + quad * 8];
        f32x4 au[8];
        #pragma unroll
        for (int t = 0; t < 8; ++t) {
            f32x4 c = {0.f, 0.f, 0.f, 0.f};
            c = __builtin_amdgcn_mfma_f32_16x16x32_bf16(af0, w1f[0][t], c, 0, 0, 0);
            c = __builtin_amdgcn_mfma_f32_16x16x32_bf16(af1, w1f[1][t], c, 0, 0, 0);
            au[t] = c;
        }
        // LN(128)+relu -> ub
        #pragma unroll
        for (int r = 0; r < 4; ++r) {
            float sx = 0.f, sq = 0.f;
            #pragma unroll
            for (int t = 0; t < 8; ++t) {
                float v = au[t][r] + b1f[t];
                sx += v; sq += v * v;
            }
            #pragma unroll
            for (int mask = 1; mask < 16; mask <<= 1) {
                sx += __shfl_xor(sx, mask, 64);
                sq += __shfl_xor(sq, mask, 64);
            }
            float mu = sx * (1.f / 128.f);
            float var = sq * (1.f / 128.f) - mu * mu;
            float rs = rsqrtf(var + 1e-5f);
            int row = quad * 4 + r;
            #pragma unroll
            for (int t = 0; t < 8; ++t) {
                float v = au[t][r] + b1f[t];
                float y = fmaxf(fmaf((v - mu) * rs, g1f[t], e1f[t]), 0.f);
                ub[row * 128 + t * 16 + col] = f2bf(y);
            }
        }
        // GEMM2
        f32x4 oc[4];
        #pragma unroll
        for (int t = 0; t < 4; ++t) oc[t] = (f32x4){0.f, 0.f, 0.f, 0.f};
        #pragma unroll
        for (int s = 0; s < 4; ++s) {
            short8 a = *(const short8*)&ub[col * 128 + s * 32 + quad * 8];
            #pragma unroll
            for (int t = 0; t < 4; ++t)
                oc[t] = __builtin_amdgcn_mfma_f32_16x16x32_bf16(a, w2f[s][t], oc[t], 0, 0, 0);
        }
        // epilogue: bias (+res) -> h / zb-in-place or pool partials
        #pragma unroll
        for (int r = 0; r < 4; ++r) {
            int n = n0 + quad * 4 + r;
            float val[4];
            #pragma unroll
            for (int t = 0; t < 4; ++t) {
                val[t] = oc[t][r] + b2f_[t];
                if (mode >= 1) val[t] += h[(size_t)n * 64 + t * 16 + col];
            }
            if (mode <= 1) {
                #pragma unroll
                for (int t = 0; t < 4; ++t) h[(size_t)n * 64 + t * 16 + col] = val[t];
            }
            // LN(64) over this node's 64 channels: 4 in-lane + intra-quad shuffles
            float sx = 0.f, sq = 0.f;
            #pragma unroll
            for (int t = 0; t < 4; ++t) { sx += val[t]; sq += val[t] * val[t]; }
            #pragma unroll
            for (int mask = 1; mask < 16; mask <<= 1) {
                sx += __shfl_xor(sx, mask, 64);
                sq += __shfl_xor(sq, mask, 64);
            }
            float mu = sx * (1.f / 64.f);
            float var = sq * (1.f / 64.f) - mu * mu;
            float rs = rsqrtf(var + 1e-5f);
            #pragma unroll
            for (int t = 0; t < 4; ++t) {
                float y = fmaxf(fmaf((val[t] - mu) * rs, ngf[t], nbf[t]), 0.f);
                if (mode <= 1) {
                    zb[(size_t)n * 64 + t * 16 + col] = f2bf(y);
                } else {
                    psum[t] += y;
                    pmax[t] = fmaxf(pmax[t], y);
                }
            }
        }
    }
    if (mode == 2) {
        #pragma unroll
        for (int t = 0; t < 4; ++t) {
            psum[t] += __shfl_xor(psum[t], 16, 64);
            psum[t] += __shfl_xor(psum[t], 32, 64);
            pmax[t] = fmaxf(pmax[t], __shfl_xor(pmax[t], 16, 64));
            pmax[t] = fmaxf(pmax[t], __shfl_xor(pmax[t], 32, 64));
        }
        if (quad == 0) {
            #pragma unroll
            for (int t = 0; t < 4; ++t) {
                lssum[wave][t][col] = psum[t];
                lsmax[wave][t][col] = pmax[t];
            }
        }
        __syncthreads();
        if (wave == 0) {
            int t = lane >> 4, c = lane & 15;   // channel = lane
            float s = lssum[0][t][c] + lssum[1][t][c] + lssum[2][t][c] + lssum[3][t][c];
            float mx = fmaxf(fmaxf(lsmax[0][t][c], lsmax[1][t][c]),
                             fmaxf(lsmax[2][t][c], lsmax[3][t][c]));
            pb_sum[blockIdx.x * 64 + lane] = s;
            pb_max[blockIdx.x * 64 + lane] = mx;
        }
    }
}

// ---------------- head: reduce block partials -> bins -> emb @ W_lin + b_lin ----------------
__global__ __launch_bounds__(256) void k_head(
    const float* __restrict__ pb_sum, const float* __restrict__ pb_max,
    const float* __restrict__ Wl, const float* __restrict__ bl, float* __restrict__ out) {
    __shared__ float sa4[4][64], sm4[4][64];
    __shared__ float sa[64], sm[64], emb[64];
    int t = threadIdx.x;
    int ch = t & 63, part = t >> 6;
    float s = 0.f, mx = 0.f;
    for (int b = part; b < NB_F; b += 4) {
        s += pb_sum[b * 64 + ch];
        mx = fmaxf(mx, pb_max[b * 64 + ch]);
    }
    sa4[part][ch] = s; sm4[part][ch] = mx;
    __syncthreads();
    if (t < 64) {
        sa[t] = sa4[0][t] + sa4[1][t] + sa4[2][t] + sa4[3][t];
        sm[t] = fmaxf(fmaxf(sm4[0][t], sm4[1][t]), fmaxf(sm4[2][t], sm4[3][t]));
    }
    __syncthreads();
    if (t < 64) {
        if (t < 32) {
            emb[t] = (sa[2 * t] + sa[2 * t + 1]) * (0.5f / (float)N_NODES);
        } else {
            int i = t - 32;
            emb[t] = fmaxf(sm[2 * i], sm[2 * i + 1]);
        }
    }
    __syncthreads();
    if (t < 64) {
        float acc = bl[t];
        for (int k = 0; k < 64; ++k) acc = fmaf(emb[k], Wl[k * 64 + t], acc);
        out[t] = acc;
    }
}

extern "C" void kernel_launch(void* const* d_in, const int* in_sizes, int n_in,
                              void* d_out, int out_size, void* d_ws, size_t ws_size,
                              hipStream_t stream) {
    const float* x     = (const float*)d_in[0];
    const float* eattr = (const float*)d_in[1];
    const int*   ei    = (const int*)d_in[2];
    const float* Wn    = (const float*)d_in[3];
    const float* bn    = (const float*)d_in[4];
    const float* We    = (const float*)d_in[5];
    const float* be    = (const float*)d_in[6];
    const float* t     = (const float*)d_in[7];
    const float* W1    = (const float*)d_in[8];
    const float* b1    = (const float*)d_in[9];
    const float* lg    = (const float*)d_in[10];
    const float* lb    = (const float*)d_in[11];
    const float* W2    = (const float*)d_in[12];
    const float* b2    = (const float*)d_in[13];
    const float* ng    = (const float*)d_in[14];
    const float* nb    = (const float*)d_in[15];
    const float* Wl    = (const float*)d_in[16];
    const float* bl    = (const float*)d_in[17];
    float* out = (float*)d_out;

    char* p = (char*)d_ws;
    float* h   = (float*)p; p += (size_t)N_NODES * 64 * 4;
    unsigned short* zb   = (unsigned short*)p; p += (size_t)N_NODES * 64 * 2;
    unsigned short* aggb = (unsigned short*)p; p += (size_t)N_NODES * 64 * 2;
    unsigned int* s_pack = (unsigned int*)p; p += (size_t)N_EDGES * 4;
    int* cnt    = (int*)p;  p += (size_t)(N_NODES + 4) * 4;
    int* offs   = (int*)p;  p += (size_t)(N_NODES + 4) * 4;
    int* inc    = (int*)p;  p += (size_t)(N_NODES + 4) * 4;
    int* bsum   = (int*)p;  p += (size_t)256 * 4;
    float* pb_sum = (float*)p; p += (size_t)NB_F * 64 * 4;
    float* pb_max = (float*)p; p += (size_t)NB_F * 64 * 4;
    int* rank = (int*)p;    p += (size_t)N_EDGES * 4;

    hipMemsetAsync(cnt, 0, (N_NODES + 1) * sizeof(int), stream);

    k_node_encode<<<(N_NODES + 3) / 4, 256, 0, stream>>>(x, Wn, bn, h, zb);
    k_hist_rank<<<(N_EDGES + 255) / 256, 256, 0, stream>>>(ei, cnt, rank);
    k_scan1<<<SCAN_NB, 256, 0, stream>>>(cnt, inc, bsum);
    k_scan2<<<1, 256, 0, stream>>>(bsum);
    k_scan3<<<SCAN_NB, 256, 0, stream>>>(inc, cnt, bsum, offs);
    k_scatter<<<(N_EDGES + 255) / 256, 256, 0, stream>>>(ei, eattr, offs, rank, s_pack);

    // layer 0: agg from zb; mlp writes h and zb <- relu(LN(h, ng[1]))
    k_agg<<<(N_NODES + 3) / 4, 256, 0, stream>>>(zb, offs, s_pack, We, be, t, 0, aggb);
    k_mlp<<<NB_F, 256, 0, stream>>>(aggb, zb, h, W1, b1, lg, lb, W2, b2,
                                    ng + 64, nb + 64, 0, pb_sum, pb_max);
    // layer 1: residual; zb <- relu(LN(h, ng[2]))
    k_agg<<<(N_NODES + 3) / 4, 256, 0, stream>>>(zb, offs, s_pack, We, be, t, 1, aggb);
    k_mlp<<<NB_F, 256, 0, stream>>>(aggb, zb, h, W1 + 64 * 128, b1 + 128, lg + 128, lb + 128,
                                    W2 + 128 * 64, b2 + 64, ng + 128, nb + 128, 1, pb_sum, pb_max);
    // layer 2: residual; pool partials with ng[0]
    k_agg<<<(N_NODES + 3) / 4, 256, 0, stream>>>(zb, offs, s_pack, We, be, t, 2, aggb);
    k_mlp<<<NB_F, 256, 0, stream>>>(aggb, zb, h, W1 + 2 * 64 * 128, b1 + 2 * 128,
                                    lg + 2 * 128, lb + 2 * 128, W2 + 2 * 128 * 64, b2 + 2 * 64,
                                    ng, nb, 2, pb_sum, pb_max);

    k_head<<<1, 256, 0, stream>>>(pb_sum, pb_max, Wl, bl, out);
}

// Round 13
// 383.974 us; speedup vs baseline: 2.8744x; 1.1163x over previous
//
#include <hip/hip_runtime.h>
#include <math.h>

#define N_NODES 50000
#define N_EDGES 1000000
#define HID 64
#define SCAN_NB ((N_NODES + 1 + 255) / 256)
#define N_TILES (N_NODES / 16)          // 3125
#define NB_F ((N_TILES + 3) / 4)        // 782 mlp blocks (4 waves each)
#define NB2 64                          // stage-2 reduction blocks
static_assert(N_NODES % 16 == 0, "tile math");
static_assert(N_NODES <= 65536, "src must fit in 16 bits");

typedef __attribute__((ext_vector_type(8))) short short8;   // 8 bf16 = 4 VGPRs
typedef __attribute__((ext_vector_type(4))) float f32x4;

__device__ __forceinline__ unsigned short f2bf(float x) {   // RNE float->bf16
    unsigned u = __float_as_uint(x);
    u += 0x7FFFu + ((u >> 16) & 1u);
    return (unsigned short)(u >> 16);
}
__device__ __forceinline__ float bfbits_hi(unsigned pk) {   // high-16 bf16 -> f32
    return __uint_as_float(pk & 0xFFFF0000u);
}
__device__ __forceinline__ float bf2f(unsigned short v) {
    return __uint_as_float(((unsigned)v) << 16);
}
// packed bf16 pair add with RNE re-round
__device__ __forceinline__ unsigned addpk(unsigned a, unsigned b) {
    float lo = __uint_as_float(a << 16) + __uint_as_float(b << 16);
    float hi = __uint_as_float(a & 0xFFFF0000u) + __uint_as_float(b & 0xFFFF0000u);
    return (unsigned)f2bf(lo) | ((unsigned)f2bf(hi) << 16);
}

// ---------------- node encoder: h = x @ W_node + b_node (f32 + bf16 copies) ----------------
__global__ __launch_bounds__(256) void k_node_encode(
    const float* __restrict__ x, const float* __restrict__ Wn,
    const float* __restrict__ bn, float* __restrict__ h, unsigned short* __restrict__ hb) {
    int n = blockIdx.x * 4 + (threadIdx.x >> 6);
    int c = threadIdx.x & 63;
    if (n >= N_NODES) return;
    float acc = bn[c];
    const float* xr = x + n * 16;
    #pragma unroll
    for (int k = 0; k < 16; ++k) acc = fmaf(xr[k], Wn[k * 64 + c], acc);
    h[n * 64 + c] = acc;
    hb[n * 64 + c] = f2bf(acc);
}

// ---------------- edge CSR build ----------------
__global__ __launch_bounds__(256) void k_hist_rank(const int* __restrict__ ei,
                                                   int* __restrict__ cnt, int* __restrict__ rank) {
    int i = blockIdx.x * blockDim.x + threadIdx.x;
    if (i >= N_EDGES) return;
    rank[i] = atomicAdd(&cnt[ei[N_EDGES + i]], 1);
}

__global__ __launch_bounds__(256) void k_scan1(const int* __restrict__ cnt,
                                               int* __restrict__ inc, int* __restrict__ bsum) {
    __shared__ int sh[256];
    int gi = blockIdx.x * 256 + threadIdx.x;
    int v = (gi < N_NODES + 1) ? cnt[gi] : 0;
    sh[threadIdx.x] = v;
    __syncthreads();
    #pragma unroll
    for (int d = 1; d < 256; d <<= 1) {
        int t = (threadIdx.x >= d) ? sh[threadIdx.x - d] : 0;
        __syncthreads();
        sh[threadIdx.x] += t;
        __syncthreads();
    }
    if (gi < N_NODES + 1) inc[gi] = sh[threadIdx.x];
    if (threadIdx.x == 255) bsum[blockIdx.x] = sh[255];
}

__global__ __launch_bounds__(256) void k_scan2(int* __restrict__ bsum) {
    __shared__ int sh[256];
    int t = threadIdx.x;
    sh[t] = (t < SCAN_NB) ? bsum[t] : 0;
    __syncthreads();
    #pragma unroll
    for (int d = 1; d < 256; d <<= 1) {
        int v = (t >= d) ? sh[t - d] : 0;
        __syncthreads();
        sh[t] += v;
        __syncthreads();
    }
    if (t < SCAN_NB) bsum[t] = (t == 0) ? 0 : sh[t - 1];
}

__global__ __launch_bounds__(256) void k_scan3(const int* __restrict__ inc,
                                               const int* __restrict__ cnt,
                                               const int* __restrict__ bsum,
                                               int* __restrict__ offs) {
    int gi = blockIdx.x * 256 + threadIdx.x;
    if (gi < N_NODES + 1) offs[gi] = bsum[blockIdx.x] + inc[gi] - cnt[gi];
}

__global__ __launch_bounds__(256) void k_scatter(
    const int* __restrict__ ei, const float* __restrict__ eattr,
    const int* __restrict__ offs, const int* __restrict__ rank,
    unsigned int* __restrict__ s_pack) {
    int i = blockIdx.x * blockDim.x + threadIdx.x;
    if (i >= N_EDGES) return;
    int d = ei[N_EDGES + i];
    int p = offs[d] + rank[i];
    unsigned pk = ((unsigned)f2bf(eattr[i]) << 16) | (unsigned)(ei[i] & 0xFFFF);
    s_pack[p] = pk;
}

// ---------------- softmax aggregation (shift-free), one wave/node, low-VGPR high-TLP ----------------
__global__ __launch_bounds__(256) void k_agg(
    const unsigned short* __restrict__ zb, const int* __restrict__ offs,
    const unsigned int* __restrict__ s_pack,
    const float* __restrict__ We, const float* __restrict__ be,
    const float* __restrict__ t, int layer, unsigned short* __restrict__ aggb) {
    int wid = (blockIdx.x * blockDim.x + threadIdx.x) >> 6;
    int lane = threadIdx.x & 63;
    if (wid >= N_NODES) return;
    int beg = offs[wid], end = offs[wid + 1];
    float we = We[lane], bev = be[lane];
    float tl = t[layer];
    float s = 0.f, num = 0.f;
    int i = beg;
    for (; i + 3 < end; i += 4) {
        unsigned pk0 = s_pack[i], pk1 = s_pack[i + 1], pk2 = s_pack[i + 2], pk3 = s_pack[i + 3];
        float z0 = bf2f(zb[(pk0 & 0xFFFFu) * 64 + lane]);
        float z1 = bf2f(zb[(pk1 & 0xFFFFu) * 64 + lane]);
        float z2 = bf2f(zb[(pk2 & 0xFFFFu) * 64 + lane]);
        float z3 = bf2f(zb[(pk3 & 0xFFFFu) * 64 + lane]);
        float msg0 = fmaxf(z0 + fmaf(bfbits_hi(pk0), we, bev), 0.f) + 1e-7f;
        float msg1 = fmaxf(z1 + fmaf(bfbits_hi(pk1), we, bev), 0.f) + 1e-7f;
        float msg2 = fmaxf(z2 + fmaf(bfbits_hi(pk2), we, bev), 0.f) + 1e-7f;
        float msg3 = fmaxf(z3 + fmaf(bfbits_hi(pk3), we, bev), 0.f) + 1e-7f;
        float p0 = __expf(msg0 * tl), p1 = __expf(msg1 * tl);
        float p2 = __expf(msg2 * tl), p3 = __expf(msg3 * tl);
        s += (p0 + p1) + (p2 + p3);
        num += fmaf(p0, msg0, p1 * msg1) + fmaf(p2, msg2, p3 * msg3);
    }
    for (; i < end; ++i) {
        unsigned pk = s_pack[i];
        float zz = bf2f(zb[(pk & 0xFFFFu) * 64 + lane]);
        float msg = fmaxf(zz + fmaf(bfbits_hi(pk), we, bev), 0.f) + 1e-7f;
        float p = __expf(msg * tl);
        s += p;
        num = fmaf(p, msg, num);
    }
    aggb[wid * 64 + lane] = f2bf(num / (s + 1e-16f));
}

// ---------------- MFMA MLP + fused epilogue ----------------
// mode 0: layer0 — no residual, write h, zb <- relu(LN(h, ng, nb)) in place
// mode 1: layer1 — residual,    write h, zb <- relu(LN(h, ng, nb)) in place
// mode 2: layer2 — residual, no h write, pool partials with ng/nb
__global__ __launch_bounds__(256) void k_mlp(
    const unsigned short* __restrict__ aggb, unsigned short* __restrict__ zb,
    float* __restrict__ h, const float* __restrict__ W1, const float* __restrict__ b1,
    const float* __restrict__ g1, const float* __restrict__ be1,
    const float* __restrict__ W2, const float* __restrict__ b2,
    const float* __restrict__ ng, const float* __restrict__ nb, int mode,
    float* __restrict__ pb_sum, float* __restrict__ pb_max) {
    __shared__ unsigned short vbuf[4][16 * 64];
    __shared__ unsigned short ubuf[4][16 * 128];
    __shared__ float lssum[4][4][16], lsmax[4][4][16];
    int lane = threadIdx.x & 63;
    int wave = threadIdx.x >> 6;
    int col = lane & 15, quad = lane >> 4;
    unsigned short* vb = vbuf[wave];
    unsigned short* ub = ubuf[wave];

    short8 w1f[2][8];
    #pragma unroll
    for (int s = 0; s < 2; ++s)
        #pragma unroll
        for (int t = 0; t < 8; ++t)
            #pragma unroll
            for (int j = 0; j < 8; ++j)
                w1f[s][t][j] = (short)f2bf(W1[(s * 32 + quad * 8 + j) * 128 + t * 16 + col]);
    short8 w2f[4][4];
    #pragma unroll
    for (int s = 0; s < 4; ++s)
        #pragma unroll
        for (int t = 0; t < 4; ++t)
            #pragma unroll
            for (int j = 0; j < 8; ++j)
                w2f[s][t][j] = (short)f2bf(W2[(s * 32 + quad * 8 + j) * 64 + t * 16 + col]);

    float b1f[8], g1f[8], e1f[8];
    #pragma unroll
    for (int t = 0; t < 8; ++t) {
        int ch = t * 16 + col;
        b1f[t] = b1[ch]; g1f[t] = g1[ch]; e1f[t] = be1[ch];
    }
    float b2f_[4], ngf[4], nbf[4];
    #pragma unroll
    for (int t = 0; t < 4; ++t) {
        b2f_[t] = b2[t * 16 + col];
        ngf[t] = ng[t * 16 + col];
        nbf[t] = nb[t * 16 + col];
    }

    float psum[4] = {0.f, 0.f, 0.f, 0.f};
    float pmax[4] = {0.f, 0.f, 0.f, 0.f};
    int nd = lane >> 2;
    int cg = (lane & 3) * 16;
    int tile = blockIdx.x * 4 + wave;

    if (tile < N_TILES) {
        int n0 = tile * 16;
        const uint4* ap = (const uint4*)(aggb + (size_t)(n0 + nd) * 64 + cg);
        const uint4* zp = (const uint4*)(zb + (size_t)(n0 + nd) * 64 + cg);
        uint4 a0 = ap[0], a1 = ap[1], z0 = zp[0], z1 = zp[1];
        uint4 r0, r1;
        r0.x = addpk(a0.x, z0.x); r0.y = addpk(a0.y, z0.y);
        r0.z = addpk(a0.z, z0.z); r0.w = addpk(a0.w, z0.w);
        r1.x = addpk(a1.x, z1.x); r1.y = addpk(a1.y, z1.y);
        r1.z = addpk(a1.z, z1.z); r1.w = addpk(a1.w, z1.w);
        uint4* vdst = (uint4*)&vb[nd * 64 + cg];
        vdst[0] = r0;
        vdst[1] = r1;

        // GEMM1
        short8 af0 = *(const short8*)&vb[col * 64 + quad * 8];
        short8 af1 = *(const short8*)&vb[col * 64 + 32 + quad * 8];
        f32x4 au[8];
        #pragma unroll
        for (int t = 0; t < 8; ++t) {
            f32x4 c = {0.f, 0.f, 0.f, 0.f};
            c = __builtin_amdgcn_mfma_f32_16x16x32_bf16(af0, w1f[0][t], c, 0, 0, 0);
            c = __builtin_amdgcn_mfma_f32_16x16x32_bf16(af1, w1f[1][t], c, 0, 0, 0);
            au[t] = c;
        }
        // LN(128)+relu -> ub
        #pragma unroll
        for (int r = 0; r < 4; ++r) {
            float sx = 0.f, sq = 0.f;
            #pragma unroll
            for (int t = 0; t < 8; ++t) {
                float v = au[t][r] + b1f[t];
                sx += v; sq += v * v;
            }
            #pragma unroll
            for (int mask = 1; mask < 16; mask <<= 1) {
                sx += __shfl_xor(sx, mask, 64);
                sq += __shfl_xor(sq, mask, 64);
            }
            float mu = sx * (1.f / 128.f);
            float var = sq * (1.f / 128.f) - mu * mu;
            float rs = rsqrtf(var + 1e-5f);
            int row = quad * 4 + r;
            #pragma unroll
            for (int t = 0; t < 8; ++t) {
                float v = au[t][r] + b1f[t];
                float y = fmaxf(fmaf((v - mu) * rs, g1f[t], e1f[t]), 0.f);
                ub[row * 128 + t * 16 + col] = f2bf(y);
            }
        }
        // GEMM2
        f32x4 oc[4];
        #pragma unroll
        for (int t = 0; t < 4; ++t) oc[t] = (f32x4){0.f, 0.f, 0.f, 0.f};
        #pragma unroll
        for (int s = 0; s < 4; ++s) {
            short8 a = *(const short8*)&ub[col * 128 + s * 32 + quad * 8];
            #pragma unroll
            for (int t = 0; t < 4; ++t)
                oc[t] = __builtin_amdgcn_mfma_f32_16x16x32_bf16(a, w2f[s][t], oc[t], 0, 0, 0);
        }
        // epilogue
        #pragma unroll
        for (int r = 0; r < 4; ++r) {
            int n = n0 + quad * 4 + r;
            float val[4];
            #pragma unroll
            for (int t = 0; t < 4; ++t) {
                val[t] = oc[t][r] + b2f_[t];
                if (mode >= 1) val[t] += h[(size_t)n * 64 + t * 16 + col];
            }
            if (mode <= 1) {
                #pragma unroll
                for (int t = 0; t < 4; ++t) h[(size_t)n * 64 + t * 16 + col] = val[t];
            }
            float sx = 0.f, sq = 0.f;
            #pragma unroll
            for (int t = 0; t < 4; ++t) { sx += val[t]; sq += val[t] * val[t]; }
            #pragma unroll
            for (int mask = 1; mask < 16; mask <<= 1) {
                sx += __shfl_xor(sx, mask, 64);
                sq += __shfl_xor(sq, mask, 64);
            }
            float mu = sx * (1.f / 64.f);
            float var = sq * (1.f / 64.f) - mu * mu;
            float rs = rsqrtf(var + 1e-5f);
            #pragma unroll
            for (int t = 0; t < 4; ++t) {
                float y = fmaxf(fmaf((val[t] - mu) * rs, ngf[t], nbf[t]), 0.f);
                if (mode <= 1) {
                    zb[(size_t)n * 64 + t * 16 + col] = f2bf(y);
                } else {
                    psum[t] += y;
                    pmax[t] = fmaxf(pmax[t], y);
                }
            }
        }
    }
    if (mode == 2) {
        #pragma unroll
        for (int t = 0; t < 4; ++t) {
            psum[t] += __shfl_xor(psum[t], 16, 64);
            psum[t] += __shfl_xor(psum[t], 32, 64);
            pmax[t] = fmaxf(pmax[t], __shfl_xor(pmax[t], 16, 64));
            pmax[t] = fmaxf(pmax[t], __shfl_xor(pmax[t], 32, 64));
        }
        if (quad == 0) {
            #pragma unroll
            for (int t = 0; t < 4; ++t) {
                lssum[wave][t][col] = psum[t];
                lsmax[wave][t][col] = pmax[t];
            }
        }
        __syncthreads();
        if (wave == 0) {
            int t = lane >> 4, c = lane & 15;
            float s = lssum[0][t][c] + lssum[1][t][c] + lssum[2][t][c] + lssum[3][t][c];
            float mx = fmaxf(fmaxf(lsmax[0][t][c], lsmax[1][t][c]),
                             fmaxf(lsmax[2][t][c], lsmax[3][t][c]));
            pb_sum[blockIdx.x * 64 + lane] = s;
            pb_max[blockIdx.x * 64 + lane] = mx;
        }
    }
}

// ---------------- stage-2 reduce: 782 partial rows -> 64 rows (64 blocks) ----------------
__global__ __launch_bounds__(256) void k_red(
    const float* __restrict__ pb_sum, const float* __restrict__ pb_max,
    float* __restrict__ p2_sum, float* __restrict__ p2_max) {
    __shared__ float sa4[4][64], sm4[4][64];
    int t = threadIdx.x;
    int ch = t & 63, part = t >> 6;
    float s = 0.f, mx = 0.f;
    for (int b = blockIdx.x + NB2 * part; b < NB_F; b += NB2 * 4) {
        s += pb_sum[b * 64 + ch];
        mx = fmaxf(mx, pb_max[b * 64 + ch]);
    }
    sa4[part][ch] = s; sm4[part][ch] = mx;
    __syncthreads();
    if (t < 64) {
        p2_sum[blockIdx.x * 64 + t] = sa4[0][t] + sa4[1][t] + sa4[2][t] + sa4[3][t];
        p2_max[blockIdx.x * 64 + t] =
            fmaxf(fmaxf(sm4[0][t], sm4[1][t]), fmaxf(sm4[2][t], sm4[3][t]));
    }
}

// ---------------- head: reduce 64 rows -> bins -> emb @ W_lin + b_lin ----------------
__global__ __launch_bounds__(256) void k_head(
    const float* __restrict__ p2_sum, const float* __restrict__ p2_max,
    const float* __restrict__ Wl, const float* __restrict__ bl, float* __restrict__ out) {
    __shared__ float sa4[4][64], sm4[4][64];
    __shared__ float sa[64], sm[64], emb[64];
    int t = threadIdx.x;
    int ch = t & 63, part = t >> 6;
    float s = 0.f, mx = 0.f;
    for (int b = part; b < NB2; b += 4) {
        s += p2_sum[b * 64 + ch];
        mx = fmaxf(mx, p2_max[b * 64 + ch]);
    }
    sa4[part][ch] = s; sm4[part][ch] = mx;
    __syncthreads();
    if (t < 64) {
        sa[t] = sa4[0][t] + sa4[1][t] + sa4[2][t] + sa4[3][t];
        sm[t] = fmaxf(fmaxf(sm4[0][t], sm4[1][t]), fmaxf(sm4[2][t], sm4[3][t]));
    }
    __syncthreads();
    if (t < 64) {
        if (t < 32) {
            emb[t] = (sa[2 * t] + sa[2 * t + 1]) * (0.5f / (float)N_NODES);
        } else {
            int i = t - 32;
            emb[t] = fmaxf(sm[2 * i], sm[2 * i + 1]);
        }
    }
    __syncthreads();
    if (t < 64) {
        float acc = bl[t];
        for (int k = 0; k < 64; ++k) acc = fmaf(emb[k], Wl[k * 64 + t], acc);
        out[t] = acc;
    }
}

extern "C" void kernel_launch(void* const* d_in, const int* in_sizes, int n_in,
                              void* d_out, int out_size, void* d_ws, size_t ws_size,
                              hipStream_t stream) {
    const float* x     = (const float*)d_in[0];
    const float* eattr = (const float*)d_in[1];
    const int*   ei    = (const int*)d_in[2];
    const float* Wn    = (const float*)d_in[3];
    const float* bn    = (const float*)d_in[4];
    const float* We    = (const float*)d_in[5];
    const float* be    = (const float*)d_in[6];
    const float* t     = (const float*)d_in[7];
    const float* W1    = (const float*)d_in[8];
    const float* b1    = (const float*)d_in[9];
    const float* lg    = (const float*)d_in[10];
    const float* lb    = (const float*)d_in[11];
    const float* W2    = (const float*)d_in[12];
    const float* b2    = (const float*)d_in[13];
    const float* ng    = (const float*)d_in[14];
    const float* nb    = (const float*)d_in[15];
    const float* Wl    = (const float*)d_in[16];
    const float* bl    = (const float*)d_in[17];
    float* out = (float*)d_out;

    char* p = (char*)d_ws;
    float* h   = (float*)p; p += (size_t)N_NODES * 64 * 4;
    unsigned short* zb   = (unsigned short*)p; p += (size_t)N_NODES * 64 * 2;
    unsigned short* aggb = (unsigned short*)p; p += (size_t)N_NODES * 64 * 2;
    unsigned int* s_pack = (unsigned int*)p; p += (size_t)N_EDGES * 4;
    int* cnt    = (int*)p;  p += (size_t)(N_NODES + 4) * 4;
    int* offs   = (int*)p;  p += (size_t)(N_NODES + 4) * 4;
    int* inc    = (int*)p;  p += (size_t)(N_NODES + 4) * 4;
    int* bsum   = (int*)p;  p += (size_t)256 * 4;
    float* pb_sum = (float*)p; p += (size_t)NB_F * 64 * 4;
    float* pb_max = (float*)p; p += (size_t)NB_F * 64 * 4;
    float* p2_sum = (float*)p; p += (size_t)NB2 * 64 * 4;
    float* p2_max = (float*)p; p += (size_t)NB2 * 64 * 4;
    int* rank = (int*)p;    p += (size_t)N_EDGES * 4;

    hipMemsetAsync(cnt, 0, (N_NODES + 1) * sizeof(int), stream);

    k_node_encode<<<(N_NODES + 3) / 4, 256, 0, stream>>>(x, Wn, bn, h, zb);
    k_hist_rank<<<(N_EDGES + 255) / 256, 256, 0, stream>>>(ei, cnt, rank);
    k_scan1<<<SCAN_NB, 256, 0, stream>>>(cnt, inc, bsum);
    k_scan2<<<1, 256, 0, stream>>>(bsum);
    k_scan3<<<SCAN_NB, 256, 0, stream>>>(inc, cnt, bsum, offs);
    k_scatter<<<(N_EDGES + 255) / 256, 256, 0, stream>>>(ei, eattr, offs, rank, s_pack);

    // layer 0: agg from zb; mlp writes h and zb <- relu(LN(h, ng[1]))
    k_agg<<<(N_NODES + 3) / 4, 256, 0, stream>>>(zb, offs, s_pack, We, be, t, 0, aggb);
    k_mlp<<<NB_F, 256, 0, stream>>>(aggb, zb, h, W1, b1, lg, lb, W2, b2,
                                    ng + 64, nb + 64, 0, pb_sum, pb_max);
    // layer 1: residual; zb <- relu(LN(h, ng[2]))
    k_agg<<<(N_NODES + 3) / 4, 256, 0, stream>>>(zb, offs, s_pack, We, be, t, 1, aggb);
    k_mlp<<<NB_F, 256, 0, stream>>>(aggb, zb, h, W1 + 64 * 128, b1 + 128, lg + 128, lb + 128,
                                    W2 + 128 * 64, b2 + 64, ng + 128, nb + 128, 1, pb_sum, pb_max);
    // layer 2: residual; pool partials with ng[0]
    k_agg<<<(N_NODES + 3) / 4, 256, 0, stream>>>(zb, offs, s_pack, We, be, t, 2, aggb);
    k_mlp<<<NB_F, 256, 0, stream>>>(aggb, zb, h, W1 + 2 * 64 * 128, b1 + 2 * 128,
                                    lg + 2 * 128, lb + 2 * 128, W2 + 2 * 128 * 64, b2 + 2 * 64,
                                    ng, nb, 2, pb_sum, pb_max);

    k_red<<<NB2, 256, 0, stream>>>(pb_sum, pb_max, p2_sum, p2_max);
    k_head<<<1, 256, 0, stream>>>(p2_sum, p2_max, Wl, bl, out);
}

// Round 14
// 375.108 us; speedup vs baseline: 2.9424x; 1.0236x over previous
//
#include <hip/hip_runtime.h>
#include <math.h>

#define N_NODES 50000
#define N_EDGES 1000000
#define HID 64
#define SCAN_NB ((N_NODES + 1 + 255) / 256)
#define N_TILES (N_NODES / 16)          // 3125
#define NB_F ((N_TILES + 3) / 4)        // 782 mlp blocks (4 waves each)
#define NB2 64                          // stage-2 reduction blocks
#define NB_NE ((N_NODES + 3) / 4)       // encode blocks
#define NB_HR ((N_EDGES + 255) / 256)   // hist blocks
static_assert(N_NODES % 16 == 0, "tile math");
static_assert(N_NODES <= 65536, "src must fit in 16 bits");

typedef __attribute__((ext_vector_type(8))) short short8;   // 8 bf16 = 4 VGPRs
typedef __attribute__((ext_vector_type(4))) float f32x4;

__device__ __forceinline__ unsigned short f2bf(float x) {   // RNE float->bf16
    unsigned u = __float_as_uint(x);
    u += 0x7FFFu + ((u >> 16) & 1u);
    return (unsigned short)(u >> 16);
}
__device__ __forceinline__ float bfbits_hi(unsigned pk) {   // high-16 bf16 -> f32
    return __uint_as_float(pk & 0xFFFF0000u);
}
__device__ __forceinline__ float bf2f(unsigned short v) {
    return __uint_as_float(((unsigned)v) << 16);
}
// packed bf16 pair add with RNE re-round
__device__ __forceinline__ unsigned addpk(unsigned a, unsigned b) {
    float lo = __uint_as_float(a << 16) + __uint_as_float(b << 16);
    float hi = __uint_as_float(a & 0xFFFF0000u) + __uint_as_float(b & 0xFFFF0000u);
    return (unsigned)f2bf(lo) | ((unsigned)f2bf(hi) << 16);
}

// ---------------- fused: node encoder (zb only) + edge histogram/rank ----------------
__global__ __launch_bounds__(256) void k_enc_hist(
    const float* __restrict__ x, const float* __restrict__ Wn,
    const float* __restrict__ bn, unsigned short* __restrict__ zb,
    const int* __restrict__ ei, int* __restrict__ cnt, int* __restrict__ rank) {
    if (blockIdx.x < NB_NE) {
        int n = blockIdx.x * 4 + (threadIdx.x >> 6);
        int c = threadIdx.x & 63;
        if (n >= N_NODES) return;
        float acc = bn[c];
        const float* xr = x + n * 16;
        #pragma unroll
        for (int k = 0; k < 16; ++k) acc = fmaf(xr[k], Wn[k * 64 + c], acc);
        zb[n * 64 + c] = f2bf(acc);
    } else {
        int i = (blockIdx.x - NB_NE) * 256 + threadIdx.x;
        if (i >= N_EDGES) return;
        rank[i] = atomicAdd(&cnt[ei[N_EDGES + i]], 1);
    }
}

__global__ __launch_bounds__(256) void k_scan1(const int* __restrict__ cnt,
                                               int* __restrict__ inc, int* __restrict__ bsum) {
    __shared__ int sh[256];
    int gi = blockIdx.x * 256 + threadIdx.x;
    int v = (gi < N_NODES + 1) ? cnt[gi] : 0;
    sh[threadIdx.x] = v;
    __syncthreads();
    #pragma unroll
    for (int d = 1; d < 256; d <<= 1) {
        int t = (threadIdx.x >= d) ? sh[threadIdx.x - d] : 0;
        __syncthreads();
        sh[threadIdx.x] += t;
        __syncthreads();
    }
    if (gi < N_NODES + 1) inc[gi] = sh[threadIdx.x];
    if (threadIdx.x == 255) bsum[blockIdx.x] = sh[255];
}

__global__ __launch_bounds__(256) void k_scan2(int* __restrict__ bsum) {
    __shared__ int sh[256];
    int t = threadIdx.x;
    sh[t] = (t < SCAN_NB) ? bsum[t] : 0;
    __syncthreads();
    #pragma unroll
    for (int d = 1; d < 256; d <<= 1) {
        int v = (t >= d) ? sh[t - d] : 0;
        __syncthreads();
        sh[t] += v;
        __syncthreads();
    }
    if (t < SCAN_NB) bsum[t] = (t == 0) ? 0 : sh[t - 1];
}

__global__ __launch_bounds__(256) void k_scan3(const int* __restrict__ inc,
                                               const int* __restrict__ cnt,
                                               const int* __restrict__ bsum,
                                               int* __restrict__ offs) {
    int gi = blockIdx.x * 256 + threadIdx.x;
    if (gi < N_NODES + 1) offs[gi] = bsum[blockIdx.x] + inc[gi] - cnt[gi];
}

__global__ __launch_bounds__(256) void k_scatter(
    const int* __restrict__ ei, const float* __restrict__ eattr,
    const int* __restrict__ offs, const int* __restrict__ rank,
    unsigned int* __restrict__ s_pack) {
    int i = blockIdx.x * blockDim.x + threadIdx.x;
    if (i >= N_EDGES) return;
    int d = ei[N_EDGES + i];
    int p = offs[d] + rank[i];
    unsigned pk = ((unsigned)f2bf(eattr[i]) << 16) | (unsigned)(ei[i] & 0xFFFF);
    s_pack[p] = pk;
}

// ---------------- softmax aggregation (shift-free), one wave/node, 8-edge ILP ----------------
__global__ __launch_bounds__(256) void k_agg(
    const unsigned short* __restrict__ zb, const int* __restrict__ offs,
    const unsigned int* __restrict__ s_pack,
    const float* __restrict__ We, const float* __restrict__ be,
    const float* __restrict__ t, int layer, unsigned short* __restrict__ aggb) {
    int wid = (blockIdx.x * blockDim.x + threadIdx.x) >> 6;
    int lane = threadIdx.x & 63;
    if (wid >= N_NODES) return;
    int beg = offs[wid], end = offs[wid + 1];
    float we = We[lane], bev = be[lane];
    float tl = t[layer];
    float s = 0.f, num = 0.f;
    int i = beg;
    for (; i + 7 < end; i += 8) {
        unsigned pk[8];
        #pragma unroll
        for (int j = 0; j < 8; ++j) pk[j] = s_pack[i + j];
        float zv[8];
        #pragma unroll
        for (int j = 0; j < 8; ++j) zv[j] = bf2f(zb[(pk[j] & 0xFFFFu) * 64 + lane]);
        float acc_s = 0.f, acc_n = 0.f;
        #pragma unroll
        for (int j = 0; j < 8; ++j) {
            float msg = fmaxf(zv[j] + fmaf(bfbits_hi(pk[j]), we, bev), 0.f) + 1e-7f;
            float p = __expf(msg * tl);
            acc_s += p;
            acc_n = fmaf(p, msg, acc_n);
        }
        s += acc_s;
        num += acc_n;
    }
    for (; i < end; ++i) {
        unsigned pk = s_pack[i];
        float zz = bf2f(zb[(pk & 0xFFFFu) * 64 + lane]);
        float msg = fmaxf(zz + fmaf(bfbits_hi(pk), we, bev), 0.f) + 1e-7f;
        float p = __expf(msg * tl);
        s += p;
        num = fmaf(p, msg, num);
    }
    aggb[wid * 64 + lane] = f2bf(num / (s + 1e-16f));
}

// ---------------- MFMA MLP + fused epilogue (h stored as bf16) ----------------
// mode 0: layer0 — no residual, write hb, zb <- relu(LN(h, ng, nb)) in place
// mode 1: layer1 — residual,    write hb, zb <- relu(LN(h, ng, nb)) in place
// mode 2: layer2 — residual, no hb write, pool partials with ng/nb
__global__ __launch_bounds__(256) void k_mlp(
    const unsigned short* __restrict__ aggb, unsigned short* __restrict__ zb,
    unsigned short* __restrict__ hb, const float* __restrict__ W1, const float* __restrict__ b1,
    const float* __restrict__ g1, const float* __restrict__ be1,
    const float* __restrict__ W2, const float* __restrict__ b2,
    const float* __restrict__ ng, const float* __restrict__ nb, int mode,
    float* __restrict__ pb_sum, float* __restrict__ pb_max) {
    __shared__ unsigned short vbuf[4][16 * 64];
    __shared__ unsigned short ubuf[4][16 * 128];
    __shared__ float lssum[4][4][16], lsmax[4][4][16];
    int lane = threadIdx.x & 63;
    int wave = threadIdx.x >> 6;
    int col = lane & 15, quad = lane >> 4;
    unsigned short* vb = vbuf[wave];
    unsigned short* ub = ubuf[wave];

    short8 w1f[2][8];
    #pragma unroll
    for (int s = 0; s < 2; ++s)
        #pragma unroll
        for (int t = 0; t < 8; ++t)
            #pragma unroll
            for (int j = 0; j < 8; ++j)
                w1f[s][t][j] = (short)f2bf(W1[(s * 32 + quad * 8 + j) * 128 + t * 16 + col]);
    short8 w2f[4][4];
    #pragma unroll
    for (int s = 0; s < 4; ++s)
        #pragma unroll
        for (int t = 0; t < 4; ++t)
            #pragma unroll
            for (int j = 0; j < 8; ++j)
                w2f[s][t][j] = (short)f2bf(W2[(s * 32 + quad * 8 + j) * 64 + t * 16 + col]);

    float b1f[8], g1f[8], e1f[8];
    #pragma unroll
    for (int t = 0; t < 8; ++t) {
        int ch = t * 16 + col;
        b1f[t] = b1[ch]; g1f[t] = g1[ch]; e1f[t] = be1[ch];
    }
    float b2f_[4], ngf[4], nbf[4];
    #pragma unroll
    for (int t = 0; t < 4; ++t) {
        b2f_[t] = b2[t * 16 + col];
        ngf[t] = ng[t * 16 + col];
        nbf[t] = nb[t * 16 + col];
    }

    float psum[4] = {0.f, 0.f, 0.f, 0.f};
    float pmax[4] = {0.f, 0.f, 0.f, 0.f};
    int nd = lane >> 2;
    int cg = (lane & 3) * 16;
    int tile = blockIdx.x * 4 + wave;

    if (tile < N_TILES) {
        int n0 = tile * 16;
        const uint4* ap = (const uint4*)(aggb + (size_t)(n0 + nd) * 64 + cg);
        const uint4* zp = (const uint4*)(zb + (size_t)(n0 + nd) * 64 + cg);
        uint4 a0 = ap[0], a1 = ap[1], z0 = zp[0], z1 = zp[1];
        uint4 r0, r1;
        r0.x = addpk(a0.x, z0.x); r0.y = addpk(a0.y, z0.y);
        r0.z = addpk(a0.z, z0.z); r0.w = addpk(a0.w, z0.w);
        r1.x = addpk(a1.x, z1.x); r1.y = addpk(a1.y, z1.y);
        r1.z = addpk(a1.z, z1.z); r1.w = addpk(a1.w, z1.w);
        uint4* vdst = (uint4*)&vb[nd * 64 + cg];
        vdst[0] = r0;
        vdst[1] = r1;

        // GEMM1
        short8 af0 = *(const short8*)&vb[col * 64 + quad * 8];
        short8 af1 = *(const short8*)&vb[col * 64 + 32 + quad * 8];
        f32x4 au[8];
        #pragma unroll
        for (int t = 0; t < 8; ++t) {
            f32x4 c = {0.f, 0.f, 0.f, 0.f};
            c = __builtin_amdgcn_mfma_f32_16x16x32_bf16(af0, w1f[0][t], c, 0, 0, 0);
            c = __builtin_amdgcn_mfma_f32_16x16x32_bf16(af1, w1f[1][t], c, 0, 0, 0);
            au[t] = c;
        }
        // LN(128)+relu -> ub
        #pragma unroll
        for (int r = 0; r < 4; ++r) {
            float sx = 0.f, sq = 0.f;
            #pragma unroll
            for (int t = 0; t < 8; ++t) {
                float v = au[t][r] + b1f[t];
                sx += v; sq += v * v;
            }
            #pragma unroll
            for (int mask = 1; mask < 16; mask <<= 1) {
                sx += __shfl_xor(sx, mask, 64);
                sq += __shfl_xor(sq, mask, 64);
            }
            float mu = sx * (1.f / 128.f);
            float var = sq * (1.f / 128.f) - mu * mu;
            float rs = rsqrtf(var + 1e-5f);
            int row = quad * 4 + r;
            #pragma unroll
            for (int t = 0; t < 8; ++t) {
                float v = au[t][r] + b1f[t];
                float y = fmaxf(fmaf((v - mu) * rs, g1f[t], e1f[t]), 0.f);
                ub[row * 128 + t * 16 + col] = f2bf(y);
            }
        }
        // GEMM2
        f32x4 oc[4];
        #pragma unroll
        for (int t = 0; t < 4; ++t) oc[t] = (f32x4){0.f, 0.f, 0.f, 0.f};
        #pragma unroll
        for (int s = 0; s < 4; ++s) {
            short8 a = *(const short8*)&ub[col * 128 + s * 32 + quad * 8];
            #pragma unroll
            for (int t = 0; t < 4; ++t)
                oc[t] = __builtin_amdgcn_mfma_f32_16x16x32_bf16(a, w2f[s][t], oc[t], 0, 0, 0);
        }
        // epilogue
        #pragma unroll
        for (int r = 0; r < 4; ++r) {
            int n = n0 + quad * 4 + r;
            float val[4];
            #pragma unroll
            for (int t = 0; t < 4; ++t) {
                val[t] = oc[t][r] + b2f_[t];
                if (mode >= 1) val[t] += bf2f(hb[(size_t)n * 64 + t * 16 + col]);
            }
            if (mode <= 1) {
                #pragma unroll
                for (int t = 0; t < 4; ++t) hb[(size_t)n * 64 + t * 16 + col] = f2bf(val[t]);
            }
            float sx = 0.f, sq = 0.f;
            #pragma unroll
            for (int t = 0; t < 4; ++t) { sx += val[t]; sq += val[t] * val[t]; }
            #pragma unroll
            for (int mask = 1; mask < 16; mask <<= 1) {
                sx += __shfl_xor(sx, mask, 64);
                sq += __shfl_xor(sq, mask, 64);
            }
            float mu = sx * (1.f / 64.f);
            float var = sq * (1.f / 64.f) - mu * mu;
            float rs = rsqrtf(var + 1e-5f);
            #pragma unroll
            for (int t = 0; t < 4; ++t) {
                float y = fmaxf(fmaf((val[t] - mu) * rs, ngf[t], nbf[t]), 0.f);
                if (mode <= 1) {
                    zb[(size_t)n * 64 + t * 16 + col] = f2bf(y);
                } else {
                    psum[t] += y;
                    pmax[t] = fmaxf(pmax[t], y);
                }
            }
        }
    }
    if (mode == 2) {
        #pragma unroll
        for (int t = 0; t < 4; ++t) {
            psum[t] += __shfl_xor(psum[t], 16, 64);
            psum[t] += __shfl_xor(psum[t], 32, 64);
            pmax[t] = fmaxf(pmax[t], __shfl_xor(pmax[t], 16, 64));
            pmax[t] = fmaxf(pmax[t], __shfl_xor(pmax[t], 32, 64));
        }
        if (quad == 0) {
            #pragma unroll
            for (int t = 0; t < 4; ++t) {
                lssum[wave][t][col] = psum[t];
                lsmax[wave][t][col] = pmax[t];
            }
        }
        __syncthreads();
        if (wave == 0) {
            int t = lane >> 4, c = lane & 15;
            float s = lssum[0][t][c] + lssum[1][t][c] + lssum[2][t][c] + lssum[3][t][c];
            float mx = fmaxf(fmaxf(lsmax[0][t][c], lsmax[1][t][c]),
                             fmaxf(lsmax[2][t][c], lsmax[3][t][c]));
            pb_sum[blockIdx.x * 64 + lane] = s;
            pb_max[blockIdx.x * 64 + lane] = mx;
        }
    }
}

// ---------------- stage-2 reduce: 782 partial rows -> 64 rows ----------------
__global__ __launch_bounds__(256) void k_red(
    const float* __restrict__ pb_sum, const float* __restrict__ pb_max,
    float* __restrict__ p2_sum, float* __restrict__ p2_max) {
    __shared__ float sa4[4][64], sm4[4][64];
    int t = threadIdx.x;
    int ch = t & 63, part = t >> 6;
    float s = 0.f, mx = 0.f;
    for (int b = blockIdx.x + NB2 * part; b < NB_F; b += NB2 * 4) {
        s += pb_sum[b * 64 + ch];
        mx = fmaxf(mx, pb_max[b * 64 + ch]);
    }
    sa4[part][ch] = s; sm4[part][ch] = mx;
    __syncthreads();
    if (t < 64) {
        p2_sum[blockIdx.x * 64 + t] = sa4[0][t] + sa4[1][t] + sa4[2][t] + sa4[3][t];
        p2_max[blockIdx.x * 64 + t] =
            fmaxf(fmaxf(sm4[0][t], sm4[1][t]), fmaxf(sm4[2][t], sm4[3][t]));
    }
}

// ---------------- head ----------------
__global__ __launch_bounds__(256) void k_head(
    const float* __restrict__ p2_sum, const float* __restrict__ p2_max,
    const float* __restrict__ Wl, const float* __restrict__ bl, float* __restrict__ out) {
    __shared__ float sa4[4][64], sm4[4][64];
    __shared__ float sa[64], sm[64], emb[64];
    int t = threadIdx.x;
    int ch = t & 63, part = t >> 6;
    float s = 0.f, mx = 0.f;
    for (int b = part; b < NB2; b += 4) {
        s += p2_sum[b * 64 + ch];
        mx = fmaxf(mx, p2_max[b * 64 + ch]);
    }
    sa4[part][ch] = s; sm4[part][ch] = mx;
    __syncthreads();
    if (t < 64) {
        sa[t] = sa4[0][t] + sa4[1][t] + sa4[2][t] + sa4[3][t];
        sm[t] = fmaxf(fmaxf(sm4[0][t], sm4[1][t]), fmaxf(sm4[2][t], sm4[3][t]));
    }
    __syncthreads();
    if (t < 64) {
        if (t < 32) {
            emb[t] = (sa[2 * t] + sa[2 * t + 1]) * (0.5f / (float)N_NODES);
        } else {
            int i = t - 32;
            emb[t] = fmaxf(sm[2 * i], sm[2 * i + 1]);
        }
    }
    __syncthreads();
    if (t < 64) {
        float acc = bl[t];
        for (int k = 0; k < 64; ++k) acc = fmaf(emb[k], Wl[k * 64 + t], acc);
        out[t] = acc;
    }
}

extern "C" void kernel_launch(void* const* d_in, const int* in_sizes, int n_in,
                              void* d_out, int out_size, void* d_ws, size_t ws_size,
                              hipStream_t stream) {
    const float* x     = (const float*)d_in[0];
    const float* eattr = (const float*)d_in[1];
    const int*   ei    = (const int*)d_in[2];
    const float* Wn    = (const float*)d_in[3];
    const float* bn    = (const float*)d_in[4];
    const float* We    = (const float*)d_in[5];
    const float* be    = (const float*)d_in[6];
    const float* t     = (const float*)d_in[7];
    const float* W1    = (const float*)d_in[8];
    const float* b1    = (const float*)d_in[9];
    const float* lg    = (const float*)d_in[10];
    const float* lb    = (const float*)d_in[11];
    const float* W2    = (const float*)d_in[12];
    const float* b2    = (const float*)d_in[13];
    const float* ng    = (const float*)d_in[14];
    const float* nb    = (const float*)d_in[15];
    const float* Wl    = (const float*)d_in[16];
    const float* bl    = (const float*)d_in[17];
    float* out = (float*)d_out;

    char* p = (char*)d_ws;
    unsigned short* hb   = (unsigned short*)p; p += (size_t)N_NODES * 64 * 2;
    unsigned short* zb   = (unsigned short*)p; p += (size_t)N_NODES * 64 * 2;
    unsigned short* aggb = (unsigned short*)p; p += (size_t)N_NODES * 64 * 2;
    unsigned int* s_pack = (unsigned int*)p; p += (size_t)N_EDGES * 4;
    int* cnt    = (int*)p;  p += (size_t)(N_NODES + 4) * 4;
    int* offs   = (int*)p;  p += (size_t)(N_NODES + 4) * 4;
    int* inc    = (int*)p;  p += (size_t)(N_NODES + 4) * 4;
    int* bsum   = (int*)p;  p += (size_t)256 * 4;
    float* pb_sum = (float*)p; p += (size_t)NB_F * 64 * 4;
    float* pb_max = (float*)p; p += (size_t)NB_F * 64 * 4;
    float* p2_sum = (float*)p; p += (size_t)NB2 * 64 * 4;
    float* p2_max = (float*)p; p += (size_t)NB2 * 64 * 4;
    int* rank = (int*)p;    p += (size_t)N_EDGES * 4;

    hipMemsetAsync(cnt, 0, (N_NODES + 1) * sizeof(int), stream);

    k_enc_hist<<<NB_NE + NB_HR, 256, 0, stream>>>(x, Wn, bn, zb, ei, cnt, rank);
    k_scan1<<<SCAN_NB, 256, 0, stream>>>(cnt, inc, bsum);
    k_scan2<<<1, 256, 0, stream>>>(bsum);
    k_scan3<<<SCAN_NB, 256, 0, stream>>>(inc, cnt, bsum, offs);
    k_scatter<<<NB_HR, 256, 0, stream>>>(ei, eattr, offs, rank, s_pack);

    // layer 0
    k_agg<<<(N_NODES + 3) / 4, 256, 0, stream>>>(zb, offs, s_pack, We, be, t, 0, aggb);
    k_mlp<<<NB_F, 256, 0, stream>>>(aggb, zb, hb, W1, b1, lg, lb, W2, b2,
                                    ng + 64, nb + 64, 0, pb_sum, pb_max);
    // layer 1
    k_agg<<<(N_NODES + 3) / 4, 256, 0, stream>>>(zb, offs, s_pack, We, be, t, 1, aggb);
    k_mlp<<<NB_F, 256, 0, stream>>>(aggb, zb, hb, W1 + 64 * 128, b1 + 128, lg + 128, lb + 128,
                                    W2 + 128 * 64, b2 + 64, ng + 128, nb + 128, 1, pb_sum, pb_max);
    // layer 2
    k_agg<<<(N_NODES + 3) / 4, 256, 0, stream>>>(zb, offs, s_pack, We, be, t, 2, aggb);
    k_mlp<<<NB_F, 256, 0, stream>>>(aggb, zb, hb, W1 + 2 * 64 * 128, b1 + 2 * 128,
                                    lg + 2 * 128, lb + 2 * 128, W2 + 2 * 128 * 64, b2 + 2 * 64,
                                    ng, nb, 2, pb_sum, pb_max);

    k_red<<<NB2, 256, 0, stream>>>(pb_sum, pb_max, p2_sum, p2_max);
    k_head<<<1, 256, 0, stream>>>(p2_sum, p2_max, Wl, bl, out);
}

// Round 15
// 371.316 us; speedup vs baseline: 2.9724x; 1.0102x over previous
//
#include <hip/hip_runtime.h>
#include <math.h>

#define N_NODES 50000
#define N_EDGES 1000000
#define HID 64
#define SCAN_NB ((N_NODES + 1 + 255) / 256)
#define N_TILES (N_NODES / 16)          // 3125
#define NB_F ((N_TILES + 3) / 4)        // 782 mlp blocks (4 waves each)
#define NB2 64                          // stage-2 reduction blocks
static_assert(N_NODES % 16 == 0, "tile math");
static_assert(N_NODES <= 65536, "src must fit in 16 bits");

typedef __attribute__((ext_vector_type(8))) short short8;   // 8 bf16 = 4 VGPRs
typedef __attribute__((ext_vector_type(4))) float f32x4;

__device__ __forceinline__ unsigned short f2bf(float x) {   // RNE float->bf16
    unsigned u = __float_as_uint(x);
    u += 0x7FFFu + ((u >> 16) & 1u);
    return (unsigned short)(u >> 16);
}
__device__ __forceinline__ float bfbits_hi(unsigned pk) {   // high-16 bf16 -> f32
    return __uint_as_float(pk & 0xFFFF0000u);
}
__device__ __forceinline__ float bf2f(unsigned short v) {
    return __uint_as_float(((unsigned)v) << 16);
}
// packed bf16 pair add with RNE re-round
__device__ __forceinline__ unsigned addpk(unsigned a, unsigned b) {
    float lo = __uint_as_float(a << 16) + __uint_as_float(b << 16);
    float hi = __uint_as_float(a & 0xFFFF0000u) + __uint_as_float(b & 0xFFFF0000u);
    return (unsigned)f2bf(lo) | ((unsigned)f2bf(hi) << 16);
}

// ---------------- node encoder: zb = bf16(x @ W_node + b_node) ----------------
__global__ __launch_bounds__(256) void k_node_encode(
    const float* __restrict__ x, const float* __restrict__ Wn,
    const float* __restrict__ bn, unsigned short* __restrict__ zb) {
    int n = blockIdx.x * 4 + (threadIdx.x >> 6);
    int c = threadIdx.x & 63;
    if (n >= N_NODES) return;
    float acc = bn[c];
    const float* xr = x + n * 16;
    #pragma unroll
    for (int k = 0; k < 16; ++k) acc = fmaf(xr[k], Wn[k * 64 + c], acc);
    zb[n * 64 + c] = f2bf(acc);
}

// ---------------- edge CSR build ----------------
__global__ __launch_bounds__(256) void k_hist_rank(const int* __restrict__ ei,
                                                   int* __restrict__ cnt, int* __restrict__ rank) {
    int i = blockIdx.x * blockDim.x + threadIdx.x;
    if (i >= N_EDGES) return;
    rank[i] = atomicAdd(&cnt[ei[N_EDGES + i]], 1);
}

__global__ __launch_bounds__(256) void k_scan1(const int* __restrict__ cnt,
                                               int* __restrict__ inc, int* __restrict__ bsum) {
    __shared__ int sh[256];
    int gi = blockIdx.x * 256 + threadIdx.x;
    int v = (gi < N_NODES + 1) ? cnt[gi] : 0;
    sh[threadIdx.x] = v;
    __syncthreads();
    #pragma unroll
    for (int d = 1; d < 256; d <<= 1) {
        int t = (threadIdx.x >= d) ? sh[threadIdx.x - d] : 0;
        __syncthreads();
        sh[threadIdx.x] += t;
        __syncthreads();
    }
    if (gi < N_NODES + 1) inc[gi] = sh[threadIdx.x];
    if (threadIdx.x == 255) bsum[blockIdx.x] = sh[255];
}

__global__ __launch_bounds__(256) void k_scan2(int* __restrict__ bsum) {
    __shared__ int sh[256];
    int t = threadIdx.x;
    sh[t] = (t < SCAN_NB) ? bsum[t] : 0;
    __syncthreads();
    #pragma unroll
    for (int d = 1; d < 256; d <<= 1) {
        int v = (t >= d) ? sh[t - d] : 0;
        __syncthreads();
        sh[t] += v;
        __syncthreads();
    }
    if (t < SCAN_NB) bsum[t] = (t == 0) ? 0 : sh[t - 1];
}

__global__ __launch_bounds__(256) void k_scan3(const int* __restrict__ inc,
                                               const int* __restrict__ cnt,
                                               const int* __restrict__ bsum,
                                               int* __restrict__ offs) {
    int gi = blockIdx.x * 256 + threadIdx.x;
    if (gi < N_NODES + 1) offs[gi] = bsum[blockIdx.x] + inc[gi] - cnt[gi];
}

__global__ __launch_bounds__(256) void k_scatter(
    const int* __restrict__ ei, const float* __restrict__ eattr,
    const int* __restrict__ offs, const int* __restrict__ rank,
    unsigned int* __restrict__ s_pack) {
    int i = blockIdx.x * blockDim.x + threadIdx.x;
    if (i >= N_EDGES) return;
    int d = ei[N_EDGES + i];
    int p = offs[d] + rank[i];
    unsigned pk = ((unsigned)f2bf(eattr[i]) << 16) | (unsigned)(ei[i] & 0xFFFF);
    s_pack[p] = pk;
}

// ---------------- softmax aggregation (shift-free), one wave/node, 8-edge ILP ----------------
__global__ __launch_bounds__(256) void k_agg(
    const unsigned short* __restrict__ zb, const int* __restrict__ offs,
    const unsigned int* __restrict__ s_pack,
    const float* __restrict__ We, const float* __restrict__ be,
    const float* __restrict__ t, int layer, unsigned short* __restrict__ aggb) {
    int wid = (blockIdx.x * blockDim.x + threadIdx.x) >> 6;
    int lane = threadIdx.x & 63;
    if (wid >= N_NODES) return;
    int beg = offs[wid], end = offs[wid + 1];
    float we = We[lane], bev = be[lane];
    float tl = t[layer];
    float s = 0.f, num = 0.f;
    int i = beg;
    for (; i + 7 < end; i += 8) {
        unsigned pk[8];
        #pragma unroll
        for (int j = 0; j < 8; ++j) pk[j] = s_pack[i + j];
        float zv[8];
        #pragma unroll
        for (int j = 0; j < 8; ++j) zv[j] = bf2f(zb[(pk[j] & 0xFFFFu) * 64 + lane]);
        float acc_s = 0.f, acc_n = 0.f;
        #pragma unroll
        for (int j = 0; j < 8; ++j) {
            float msg = fmaxf(zv[j] + fmaf(bfbits_hi(pk[j]), we, bev), 0.f) + 1e-7f;
            float p = __expf(msg * tl);
            acc_s += p;
            acc_n = fmaf(p, msg, acc_n);
        }
        s += acc_s;
        num += acc_n;
    }
    for (; i < end; ++i) {
        unsigned pk = s_pack[i];
        float zz = bf2f(zb[(pk & 0xFFFFu) * 64 + lane]);
        float msg = fmaxf(zz + fmaf(bfbits_hi(pk), we, bev), 0.f) + 1e-7f;
        float p = __expf(msg * tl);
        s += p;
        num = fmaf(p, msg, num);
    }
    aggb[wid * 64 + lane] = f2bf(num / (s + 1e-16f));
}

// ---------------- MFMA MLP + fused epilogue (h stored as bf16) ----------------
// mode 0: layer0 — no residual, write hb, zb <- relu(LN(h, ng, nb)) in place
// mode 1: layer1 — residual,    write hb, zb <- relu(LN(h, ng, nb)) in place
// mode 2: layer2 — residual, no hb write, pool partials with ng/nb
__global__ __launch_bounds__(256) void k_mlp(
    const unsigned short* __restrict__ aggb, unsigned short* __restrict__ zb,
    unsigned short* __restrict__ hb, const float* __restrict__ W1, const float* __restrict__ b1,
    const float* __restrict__ g1, const float* __restrict__ be1,
    const float* __restrict__ W2, const float* __restrict__ b2,
    const float* __restrict__ ng, const float* __restrict__ nb, int mode,
    float* __restrict__ pb_sum, float* __restrict__ pb_max) {
    __shared__ unsigned short vbuf[4][16 * 64];
    __shared__ unsigned short ubuf[4][16 * 128];
    __shared__ float lssum[4][4][16], lsmax[4][4][16];
    int lane = threadIdx.x & 63;
    int wave = threadIdx.x >> 6;
    int col = lane & 15, quad = lane >> 4;
    unsigned short* vb = vbuf[wave];
    unsigned short* ub = ubuf[wave];

    short8 w1f[2][8];
    #pragma unroll
    for (int s = 0; s < 2; ++s)
        #pragma unroll
        for (int t = 0; t < 8; ++t)
            #pragma unroll
            for (int j = 0; j < 8; ++j)
                w1f[s][t][j] = (short)f2bf(W1[(s * 32 + quad * 8 + j) * 128 + t * 16 + col]);
    short8 w2f[4][4];
    #pragma unroll
    for (int s = 0; s < 4; ++s)
        #pragma unroll
        for (int t = 0; t < 4; ++t)
            #pragma unroll
            for (int j = 0; j < 8; ++j)
                w2f[s][t][j] = (short)f2bf(W2[(s * 32 + quad * 8 + j) * 64 + t * 16 + col]);

    float b1f[8], g1f[8], e1f[8];
    #pragma unroll
    for (int t = 0; t < 8; ++t) {
        int ch = t * 16 + col;
        b1f[t] = b1[ch]; g1f[t] = g1[ch]; e1f[t] = be1[ch];
    }
    float b2f_[4], ngf[4], nbf[4];
    #pragma unroll
    for (int t = 0; t < 4; ++t) {
        b2f_[t] = b2[t * 16 + col];
        ngf[t] = ng[t * 16 + col];
        nbf[t] = nb[t * 16 + col];
    }

    float psum[4] = {0.f, 0.f, 0.f, 0.f};
    float pmax[4] = {0.f, 0.f, 0.f, 0.f};
    int nd = lane >> 2;
    int cg = (lane & 3) * 16;
    int tile = blockIdx.x * 4 + wave;

    if (tile < N_TILES) {
        int n0 = tile * 16;
        const uint4* ap = (const uint4*)(aggb + (size_t)(n0 + nd) * 64 + cg);
        const uint4* zp = (const uint4*)(zb + (size_t)(n0 + nd) * 64 + cg);
        uint4 a0 = ap[0], a1 = ap[1], z0 = zp[0], z1 = zp[1];
        uint4 r0, r1;
        r0.x = addpk(a0.x, z0.x); r0.y = addpk(a0.y, z0.y);
        r0.z = addpk(a0.z, z0.z); r0.w = addpk(a0.w, z0.w);
        r1.x = addpk(a1.x, z1.x); r1.y = addpk(a1.y, z1.y);
        r1.z = addpk(a1.z, z1.z); r1.w = addpk(a1.w, z1.w);
        uint4* vdst = (uint4*)&vb[nd * 64 + cg];
        vdst[0] = r0;
        vdst[1] = r1;

        // GEMM1
        short8 af0 = *(const short8*)&vb[col * 64 + quad * 8];
        short8 af1 = *(const short8*)&vb[col * 64 + 32 + quad * 8];
        f32x4 au[8];
        #pragma unroll
        for (int t = 0; t < 8; ++t) {
            f32x4 c = {0.f, 0.f, 0.f, 0.f};
            c = __builtin_amdgcn_mfma_f32_16x16x32_bf16(af0, w1f[0][t], c, 0, 0, 0);
            c = __builtin_amdgcn_mfma_f32_16x16x32_bf16(af1, w1f[1][t], c, 0, 0, 0);
            au[t] = c;
        }
        // LN(128)+relu -> ub
        #pragma unroll
        for (int r = 0; r < 4; ++r) {
            float sx = 0.f, sq = 0.f;
            #pragma unroll
            for (int t = 0; t < 8; ++t) {
                float v = au[t][r] + b1f[t];
                sx += v; sq += v * v;
            }
            #pragma unroll
            for (int mask = 1; mask < 16; mask <<= 1) {
                sx += __shfl_xor(sx, mask, 64);
                sq += __shfl_xor(sq, mask, 64);
            }
            float mu = sx * (1.f / 128.f);
            float var = sq * (1.f / 128.f) - mu * mu;
            float rs = rsqrtf(var + 1e-5f);
            int row = quad * 4 + r;
            #pragma unroll
            for (int t = 0; t < 8; ++t) {
                float v = au[t][r] + b1f[t];
                float y = fmaxf(fmaf((v - mu) * rs, g1f[t], e1f[t]), 0.f);
                ub[row * 128 + t * 16 + col] = f2bf(y);
            }
        }
        // GEMM2
        f32x4 oc[4];
        #pragma unroll
        for (int t = 0; t < 4; ++t) oc[t] = (f32x4){0.f, 0.f, 0.f, 0.f};
        #pragma unroll
        for (int s = 0; s < 4; ++s) {
            short8 a = *(const short8*)&ub[col * 128 + s * 32 + quad * 8];
            #pragma unroll
            for (int t = 0; t < 4; ++t)
                oc[t] = __builtin_amdgcn_mfma_f32_16x16x32_bf16(a, w2f[s][t], oc[t], 0, 0, 0);
        }
        // epilogue
        #pragma unroll
        for (int r = 0; r < 4; ++r) {
            int n = n0 + quad * 4 + r;
            float val[4];
            #pragma unroll
            for (int t = 0; t < 4; ++t) {
                val[t] = oc[t][r] + b2f_[t];
                if (mode >= 1) val[t] += bf2f(hb[(size_t)n * 64 + t * 16 + col]);
            }
            if (mode <= 1) {
                #pragma unroll
                for (int t = 0; t < 4; ++t) hb[(size_t)n * 64 + t * 16 + col] = f2bf(val[t]);
            }
            float sx = 0.f, sq = 0.f;
            #pragma unroll
            for (int t = 0; t < 4; ++t) { sx += val[t]; sq += val[t] * val[t]; }
            #pragma unroll
            for (int mask = 1; mask < 16; mask <<= 1) {
                sx += __shfl_xor(sx, mask, 64);
                sq += __shfl_xor(sq, mask, 64);
            }
            float mu = sx * (1.f / 64.f);
            float var = sq * (1.f / 64.f) - mu * mu;
            float rs = rsqrtf(var + 1e-5f);
            #pragma unroll
            for (int t = 0; t < 4; ++t) {
                float y = fmaxf(fmaf((val[t] - mu) * rs, ngf[t], nbf[t]), 0.f);
                if (mode <= 1) {
                    zb[(size_t)n * 64 + t * 16 + col] = f2bf(y);
                } else {
                    psum[t] += y;
                    pmax[t] = fmaxf(pmax[t], y);
                }
            }
        }
    }
    if (mode == 2) {
        #pragma unroll
        for (int t = 0; t < 4; ++t) {
            psum[t] += __shfl_xor(psum[t], 16, 64);
            psum[t] += __shfl_xor(psum[t], 32, 64);
            pmax[t] = fmaxf(pmax[t], __shfl_xor(pmax[t], 16, 64));
            pmax[t] = fmaxf(pmax[t], __shfl_xor(pmax[t], 32, 64));
        }
        if (quad == 0) {
            #pragma unroll
            for (int t = 0; t < 4; ++t) {
                lssum[wave][t][col] = psum[t];
                lsmax[wave][t][col] = pmax[t];
            }
        }
        __syncthreads();
        if (wave == 0) {
            int t = lane >> 4, c = lane & 15;
            float s = lssum[0][t][c] + lssum[1][t][c] + lssum[2][t][c] + lssum[3][t][c];
            float mx = fmaxf(fmaxf(lsmax[0][t][c], lsmax[1][t][c]),
                             fmaxf(lsmax[2][t][c], lsmax[3][t][c]));
            pb_sum[blockIdx.x * 64 + lane] = s;
            pb_max[blockIdx.x * 64 + lane] = mx;
        }
    }
}

// ---------------- stage-2 reduce: 782 partial rows -> 64 rows ----------------
__global__ __launch_bounds__(256) void k_red(
    const float* __restrict__ pb_sum, const float* __restrict__ pb_max,
    float* __restrict__ p2_sum, float* __restrict__ p2_max) {
    __shared__ float sa4[4][64], sm4[4][64];
    int t = threadIdx.x;
    int ch = t & 63, part = t >> 6;
    float s = 0.f, mx = 0.f;
    for (int b = blockIdx.x + NB2 * part; b < NB_F; b += NB2 * 4) {
        s += pb_sum[b * 64 + ch];
        mx = fmaxf(mx, pb_max[b * 64 + ch]);
    }
    sa4[part][ch] = s; sm4[part][ch] = mx;
    __syncthreads();
    if (t < 64) {
        p2_sum[blockIdx.x * 64 + t] = sa4[0][t] + sa4[1][t] + sa4[2][t] + sa4[3][t];
        p2_max[blockIdx.x * 64 + t] =
            fmaxf(fmaxf(sm4[0][t], sm4[1][t]), fmaxf(sm4[2][t], sm4[3][t]));
    }
}

// ---------------- head ----------------
__global__ __launch_bounds__(256) void k_head(
    const float* __restrict__ p2_sum, const float* __restrict__ p2_max,
    const float* __restrict__ Wl, const float* __restrict__ bl, float* __restrict__ out) {
    __shared__ float sa4[4][64], sm4[4][64];
    __shared__ float sa[64], sm[64], emb[64];
    int t = threadIdx.x;
    int ch = t & 63, part = t >> 6;
    float s = 0.f, mx = 0.f;
    for (int b = part; b < NB2; b += 4) {
        s += p2_sum[b * 64 + ch];
        mx = fmaxf(mx, p2_max[b * 64 + ch]);
    }
    sa4[part][ch] = s; sm4[part][ch] = mx;
    __syncthreads();
    if (t < 64) {
        sa[t] = sa4[0][t] + sa4[1][t] + sa4[2][t] + sa4[3][t];
        sm[t] = fmaxf(fmaxf(sm4[0][t], sm4[1][t]), fmaxf(sm4[2][t], sm4[3][t]));
    }
    __syncthreads();
    if (t < 64) {
        if (t < 32) {
            emb[t] = (sa[2 * t] + sa[2 * t + 1]) * (0.5f / (float)N_NODES);
        } else {
            int i = t - 32;
            emb[t] = fmaxf(sm[2 * i], sm[2 * i + 1]);
        }
    }
    __syncthreads();
    if (t < 64) {
        float acc = bl[t];
        for (int k = 0; k < 64; ++k) acc = fmaf(emb[k], Wl[k * 64 + t], acc);
        out[t] = acc;
    }
}

extern "C" void kernel_launch(void* const* d_in, const int* in_sizes, int n_in,
                              void* d_out, int out_size, void* d_ws, size_t ws_size,
                              hipStream_t stream) {
    const float* x     = (const float*)d_in[0];
    const float* eattr = (const float*)d_in[1];
    const int*   ei    = (const int*)d_in[2];
    const float* Wn    = (const float*)d_in[3];
    const float* bn    = (const float*)d_in[4];
    const float* We    = (const float*)d_in[5];
    const float* be    = (const float*)d_in[6];
    const float* t     = (const float*)d_in[7];
    const float* W1    = (const float*)d_in[8];
    const float* b1    = (const float*)d_in[9];
    const float* lg    = (const float*)d_in[10];
    const float* lb    = (const float*)d_in[11];
    const float* W2    = (const float*)d_in[12];
    const float* b2    = (const float*)d_in[13];
    const float* ng    = (const float*)d_in[14];
    const float* nb    = (const float*)d_in[15];
    const float* Wl    = (const float*)d_in[16];
    const float* bl    = (const float*)d_in[17];
    float* out = (float*)d_out;

    char* p = (char*)d_ws;
    unsigned short* hb   = (unsigned short*)p; p += (size_t)N_NODES * 64 * 2;
    unsigned short* zb   = (unsigned short*)p; p += (size_t)N_NODES * 64 * 2;
    unsigned short* aggb = (unsigned short*)p; p += (size_t)N_NODES * 64 * 2;
    unsigned int* s_pack = (unsigned int*)p; p += (size_t)N_EDGES * 4;
    int* cnt    = (int*)p;  p += (size_t)(N_NODES + 4) * 4;
    int* offs   = (int*)p;  p += (size_t)(N_NODES + 4) * 4;
    int* inc    = (int*)p;  p += (size_t)(N_NODES + 4) * 4;
    int* bsum   = (int*)p;  p += (size_t)256 * 4;
    float* pb_sum = (float*)p; p += (size_t)NB_F * 64 * 4;
    float* pb_max = (float*)p; p += (size_t)NB_F * 64 * 4;
    float* p2_sum = (float*)p; p += (size_t)NB2 * 64 * 4;
    float* p2_max = (float*)p; p += (size_t)NB2 * 64 * 4;
    int* rank = (int*)p;    p += (size_t)N_EDGES * 4;

    hipMemsetAsync(cnt, 0, (N_NODES + 1) * sizeof(int), stream);

    k_node_encode<<<(N_NODES + 3) / 4, 256, 0, stream>>>(x, Wn, bn, zb);
    k_hist_rank<<<(N_EDGES + 255) / 256, 256, 0, stream>>>(ei, cnt, rank);
    k_scan1<<<SCAN_NB, 256, 0, stream>>>(cnt, inc, bsum);
    k_scan2<<<1, 256, 0, stream>>>(bsum);
    k_scan3<<<SCAN_NB, 256, 0, stream>>>(inc, cnt, bsum, offs);
    k_scatter<<<(N_EDGES + 255) / 256, 256, 0, stream>>>(ei, eattr, offs, rank, s_pack);

    // layer 0
    k_agg<<<(N_NODES + 3) / 4, 256, 0, stream>>>(zb, offs, s_pack, We, be, t, 0, aggb);
    k_mlp<<<NB_F, 256, 0, stream>>>(aggb, zb, hb, W1, b1, lg, lb, W2, b2,
                                    ng + 64, nb + 64, 0, pb_sum, pb_max);
    // layer 1
    k_agg<<<(N_NODES + 3) / 4, 256, 0, stream>>>(zb, offs, s_pack, We, be, t, 1, aggb);
    k_mlp<<<NB_F, 256, 0, stream>>>(aggb, zb, hb, W1 + 64 * 128, b1 + 128, lg + 128, lb + 128,
                                    W2 + 128 * 64, b2 + 64, ng + 128, nb + 128, 1, pb_sum, pb_max);
    // layer 2
    k_agg<<<(N_NODES + 3) / 4, 256, 0, stream>>>(zb, offs, s_pack, We, be, t, 2, aggb);
    k_mlp<<<NB_F, 256, 0, stream>>>(aggb, zb, hb, W1 + 2 * 64 * 128, b1 + 2 * 128,
                                    lg + 2 * 128, lb + 2 * 128, W2 + 2 * 128 * 64, b2 + 2 * 64,
                                    ng, nb, 2, pb_sum, pb_max);

    k_red<<<NB2, 256, 0, stream>>>(pb_sum, pb_max, p2_sum, p2_max);
    k_head<<<1, 256, 0, stream>>>(p2_sum, p2_max, Wl, bl, out);
}